// Round 13
// baseline (752.770 us; speedup 1.0000x reference)
//
#include <hip/hip_runtime.h>
#include <hip/hip_fp16.h>

#define NN 30000
#define NE 400000
#define NBUCK 59     // ceil(30000/512)
#define BPR 98       // blocks per relation in csr_binA: ceil(400000/4096)
#define EPB 4096     // edges per block in csr_binA
#define CAPREG 12288 // fixed slots per (rel,bucket) in binned scratch (mean 6827, sigma 82)
#define BCAP 12288   // LDS sort capacity in csr_binB

__constant__ int d_SRC[10] = {0,1,2,3,0,1,2,1,3,1};
__constant__ int d_DST[10] = {0,1,2,3,1,0,1,2,1,3};
// gather_agg2 relation order grouped by src type (L2 slice reuse)
__constant__ int d_RORD[10] = {1,5,7,9,0,4,2,6,3,8};
// fusion tables: per dst type, relations ending there
__constant__ int d_FCNT[4] = {2,4,2,2};
__constant__ int d_FREL[4][4] = {{0,5,0,0},{1,4,6,8},{2,7,0,0},{3,9,0,0}};

// XCD-pinned schedule for gather_agg1_all: block g -> xcd = g%8 (HW round-robin),
// slot = g/8 in [0,9375). Each XCD serves at most 2 relations.
__constant__ int d_XRELA[8]  = {0,4,2,6,8,1,5,7};
__constant__ int d_XBASEA[8] = {0,1875,3750,5625,0,1875,3750,5625};
__constant__ int d_XCNTA[8]  = {7500,5625,3750,1875,7500,5625,3750,1875};
__constant__ int d_XRELB[8]  = {4,2,6,3,1,5,7,9};

typedef _Float16 f16x8 __attribute__((ext_vector_type(8)));
typedef float f32x4 __attribute__((ext_vector_type(4)));

struct __attribute__((aligned(8))) h2x2 { __half2 a, b; };

// ---------------- layer-1 projection: 4 node types, ONE dispatch, BN=128 ---------
// BM=128, BK=32, full N=128 per block (A read ONCE). fp32 A -> fp16 staging.
__global__ __launch_bounds__(256)
void proj1_k(const float* __restrict__ A0, const float* __restrict__ A1,
             const float* __restrict__ A2, const float* __restrict__ A3,
             const float* __restrict__ B, const float* __restrict__ bias,
             __half* __restrict__ C)
{
    constexpr int BM = 128, BK = 32, MR = 2, NF = 8, LDK = BK + 8;
    constexpr int K = 256, N = 128, M = NN;
    const int z = blockIdx.z;
    const float* A = (z == 0) ? A0 : (z == 1) ? A1 : (z == 2) ? A2 : A3;
    const float* Bz = B + (long)z * K * N;
    const float* bz = bias + z * N;
    __half* Cz = C + (long)z * M * N;
    const int m0 = blockIdx.x * BM;
    const int tid = threadIdx.x;
    const int wv = tid >> 6;
    const int l  = tid & 63;
    const int fm = l & 15;
    const int fg = l >> 4;

    __shared__ _Float16 As[BM][LDK];
    __shared__ _Float16 Bs[128][LDK];

    f32x4 acc[MR][NF];
#pragma unroll
    for (int mr = 0; mr < MR; ++mr)
#pragma unroll
        for (int f = 0; f < NF; ++f) acc[mr][f] = (f32x4){0.f, 0.f, 0.f, 0.f};

    const int arow = tid >> 1;
    const int akc  = (tid & 1) << 4;
    const int grow = m0 + arow;

    for (int k0 = 0; k0 < K; k0 += BK) {
        f16x8 ap0, ap1;
        if (grow < M) {
            const float* aq = A + (long)grow * K + k0 + akc;
            float4 u0 = *(const float4*)aq;
            float4 u1 = *(const float4*)(aq + 4);
            float4 u2 = *(const float4*)(aq + 8);
            float4 u3 = *(const float4*)(aq + 12);
            float v[16] = {u0.x,u0.y,u0.z,u0.w, u1.x,u1.y,u1.z,u1.w,
                           u2.x,u2.y,u2.z,u2.w, u3.x,u3.y,u3.z,u3.w};
#pragma unroll
            for (int j = 0; j < 8; ++j) { ap0[j] = (_Float16)v[j]; ap1[j] = (_Float16)v[j+8]; }
        } else {
#pragma unroll
            for (int j = 0; j < 8; ++j) { ap0[j] = (_Float16)0.f; ap1[j] = (_Float16)0.f; }
        }
        *(f16x8*)&As[arow][akc]     = ap0;
        *(f16x8*)&As[arow][akc + 8] = ap1;

        {
            const int bk = tid >> 4;            // 0..15, k-rows bk and bk+16
            const int bn = (tid & 15) << 3;     // 8 cols per thread
#pragma unroll
            for (int kk = 0; kk < 2; ++kk) {
                int kr = bk + kk * 16;
                const float* bp = Bz + (long)(k0 + kr) * N + bn;
                float4 u0 = *(const float4*)bp;
                float4 u1 = *(const float4*)(bp + 4);
                Bs[bn + 0][kr] = (_Float16)u0.x;
                Bs[bn + 1][kr] = (_Float16)u0.y;
                Bs[bn + 2][kr] = (_Float16)u0.z;
                Bs[bn + 3][kr] = (_Float16)u0.w;
                Bs[bn + 4][kr] = (_Float16)u1.x;
                Bs[bn + 5][kr] = (_Float16)u1.y;
                Bs[bn + 6][kr] = (_Float16)u1.z;
                Bs[bn + 7][kr] = (_Float16)u1.w;
            }
        }
        __syncthreads();

        f16x8 a0 = *(const f16x8*)&As[wv * 32 + fm][fg * 8];
        f16x8 a1 = *(const f16x8*)&As[wv * 32 + 16 + fm][fg * 8];
#pragma unroll
        for (int f = 0; f < NF; ++f) {
            f16x8 b = *(const f16x8*)&Bs[f * 16 + fm][fg * 8];
            acc[0][f] = __builtin_amdgcn_mfma_f32_16x16x32_f16(a0, b, acc[0][f], 0, 0, 0);
            acc[1][f] = __builtin_amdgcn_mfma_f32_16x16x32_f16(a1, b, acc[1][f], 0, 0, 0);
        }
        __syncthreads();
    }

#pragma unroll
    for (int f = 0; f < NF; ++f) {
        float bzv = bz[f * 16 + fm];
#pragma unroll
        for (int mr = 0; mr < MR; ++mr)
#pragma unroll
            for (int i = 0; i < 4; ++i) {
                int gr = m0 + wv * 32 + mr * 16 + fg * 4 + i;
                if (gr < M) Cz[(long)gr * N + f * 16 + fm] = __float2half(acc[mr][f][i] + bzv);
            }
    }
}

// ---------------- MFMA GEMM (fp16 A): C[M,N] = act(A)[M,K] @ B[K,N] + bias ----
// BN in {128, 32}. epi=1: tanh + column-sum -> atomicAdd C[N]. epi=2: store fp16.
template<int BN>
__global__ __launch_bounds__(256)
void mgemm_k(const _Float16* __restrict__ Ah, long sA,
             const float* __restrict__ B, long sB,
             const float* __restrict__ bias, long sBias,
             float* __restrict__ C, long sC,
             int M, int K, int N, int relu_a, int epi)
{
    constexpr int BM = 128, BK = 32, MR = 2;
    constexpr int NF = BN / 16;
    constexpr int LDK = BK + 8;
    const int z = blockIdx.z;
    Ah += (long)z * sA;
    B += (long)z * sB;
    bias += (long)z * sBias;
    C += (long)z * sC;
    const int m0 = blockIdx.x * BM;
    const int n0 = blockIdx.y * BN;
    const int tid = threadIdx.x;
    const int wv = tid >> 6;
    const int l  = tid & 63;
    const int fm = l & 15;
    const int fg = l >> 4;

    __shared__ _Float16 As[BM][LDK];
    __shared__ _Float16 Bs[BN][LDK];
    __shared__ float red[4][BN];

    f32x4 acc[MR][NF];
#pragma unroll
    for (int mr = 0; mr < MR; ++mr)
#pragma unroll
        for (int f = 0; f < NF; ++f) acc[mr][f] = (f32x4){0.f, 0.f, 0.f, 0.f};

    const int arow = tid >> 1;
    const int akc  = (tid & 1) << 4;
    const int grow = m0 + arow;

    for (int k0 = 0; k0 < K; k0 += BK) {
        f16x8 ap0, ap1;
        if (grow < M) {
            const _Float16* aq = Ah + (long)grow * K + k0 + akc;
            ap0 = *(const f16x8*)aq;
            ap1 = *(const f16x8*)(aq + 8);
            if (relu_a) {
#pragma unroll
                for (int j = 0; j < 8; ++j) {
                    ap0[j] = ap0[j] > (_Float16)0.f ? ap0[j] : (_Float16)0.f;
                    ap1[j] = ap1[j] > (_Float16)0.f ? ap1[j] : (_Float16)0.f;
                }
            }
        } else {
#pragma unroll
            for (int j = 0; j < 8; ++j) { ap0[j] = (_Float16)0.f; ap1[j] = (_Float16)0.f; }
        }
        *(f16x8*)&As[arow][akc]     = ap0;
        *(f16x8*)&As[arow][akc + 8] = ap1;

        if constexpr (BN == 128) {
            const int bk = tid >> 4;
            const int bn = (tid & 15) << 3;
#pragma unroll
            for (int kk = 0; kk < 2; ++kk) {
                int kr = bk + kk * 16;
                const float* bp = B + (long)(k0 + kr) * N + n0 + bn;
                float4 u0 = *(const float4*)bp;
                float4 u1 = *(const float4*)(bp + 4);
                Bs[bn + 0][kr] = (_Float16)u0.x;
                Bs[bn + 1][kr] = (_Float16)u0.y;
                Bs[bn + 2][kr] = (_Float16)u0.z;
                Bs[bn + 3][kr] = (_Float16)u0.w;
                Bs[bn + 4][kr] = (_Float16)u1.x;
                Bs[bn + 5][kr] = (_Float16)u1.y;
                Bs[bn + 6][kr] = (_Float16)u1.z;
                Bs[bn + 7][kr] = (_Float16)u1.w;
            }
        } else {                                 // BN == 32
            const int bk = tid >> 3;
            const int bn = (tid & 7) << 2;
            float4 u = *(const float4*)(B + (long)(k0 + bk) * N + n0 + bn);
            Bs[bn + 0][bk] = (_Float16)u.x;
            Bs[bn + 1][bk] = (_Float16)u.y;
            Bs[bn + 2][bk] = (_Float16)u.z;
            Bs[bn + 3][bk] = (_Float16)u.w;
        }
        __syncthreads();

        f16x8 a0 = *(const f16x8*)&As[wv * 32 + fm][fg * 8];
        f16x8 a1 = *(const f16x8*)&As[wv * 32 + 16 + fm][fg * 8];
#pragma unroll
        for (int f = 0; f < NF; ++f) {
            f16x8 b = *(const f16x8*)&Bs[f * 16 + fm][fg * 8];
            acc[0][f] = __builtin_amdgcn_mfma_f32_16x16x32_f16(a0, b, acc[0][f], 0, 0, 0);
            acc[1][f] = __builtin_amdgcn_mfma_f32_16x16x32_f16(a1, b, acc[1][f], 0, 0, 0);
        }
        __syncthreads();
    }

    if (epi == 2) {
        __half* Ch = (__half*)C;
#pragma unroll
        for (int f = 0; f < NF; ++f) {
            float bz = bias[n0 + f * 16 + fm];
#pragma unroll
            for (int mr = 0; mr < MR; ++mr)
#pragma unroll
                for (int i = 0; i < 4; ++i) {
                    int gr = m0 + wv * 32 + mr * 16 + fg * 4 + i;
                    if (gr < M) Ch[(long)gr * N + n0 + f * 16 + fm] = __float2half(acc[mr][f][i] + bz);
                }
        }
    } else {
#pragma unroll
        for (int f = 0; f < NF; ++f) {
            float bz = bias[n0 + f * 16 + fm];
            float s = 0.f;
#pragma unroll
            for (int mr = 0; mr < MR; ++mr)
#pragma unroll
                for (int i = 0; i < 4; ++i) {
                    int gr = m0 + wv * 32 + mr * 16 + fg * 4 + i;
                    if (gr < M) s += tanhf(acc[mr][f][i] + bz);
                }
            s += __shfl_xor(s, 16, 64);
            s += __shfl_xor(s, 32, 64);
            if (fg == 0) red[wv][f * 16 + fm] = s;
        }
        __syncthreads();
        if (tid < BN) {
            float s = red[0][tid] + red[1][tid] + red[2][tid] + red[3][tid];
            unsafeAtomicAdd(&C[n0 + tid], s);
        }
    }
}

// ---------------- init: bucket cursors + colsum zeroing ----------------
__global__ __launch_bounds__(256)
void init_k(int* __restrict__ binCur, float* __restrict__ colsum)
{
    int i = blockIdx.x * 256 + threadIdx.x;
    if (i < 10 * NBUCK) binCur[i] = (i % NBUCK) * CAPREG;
    if (i < 1632) colsum[i] = 0.f;
}

__global__ __launch_bounds__(256)
void csr_binA(const int* __restrict__ edges, int* __restrict__ binCur,
              unsigned* __restrict__ binned)
{
    __shared__ int lcnt[NBUCK];
    __shared__ int gbase[NBUCK];
    int rel = blockIdx.x / BPR;
    int blk = blockIdx.x - rel * BPR;
    int base = blk * EPB;
    int tid = threadIdx.x;
    for (int b = tid; b < NBUCK; b += 256) lcnt[b] = 0;
    __syncthreads();
    const int* er = edges + (long)rel * 2 * NE;
    const int* ec = er + NE;
    unsigned pk[16];
    unsigned mt[16];
#pragma unroll
    for (int k = 0; k < 16; ++k) {
        int i = base + k * 256 + tid;
        if (i < NE) {
            int r = er[i];
            int c = ec[i];
            int b = c >> 9;
            int lo = atomicAdd(&lcnt[b], 1);
            pk[k] = ((unsigned)c << 15) | (unsigned)r;
            mt[k] = ((unsigned)b << 16) | (unsigned)lo;
        } else {
            mt[k] = 0xFFFFFFFFu;
        }
    }
    __syncthreads();
    if (tid < NBUCK) gbase[tid] = atomicAdd(&binCur[rel * NBUCK + tid], lcnt[tid]);
    __syncthreads();
    unsigned* bn = binned + (long)rel * NBUCK * CAPREG;
#pragma unroll
    for (int k = 0; k < 16; ++k) {
        if (mt[k] != 0xFFFFFFFFu) {
            int b = mt[k] >> 16;
            int lo = mt[k] & 0xFFFF;
            bn[gbase[b] + lo] = pk[k];
        }
    }
}

// Pass B: per (rel,bucket) block: per-node histogram + scan -> csr_off segment;
// LDS sort; coalesced stream-out (u16 rows). Bucket CSR base computed inline.
__global__ __launch_bounds__(256)
void csr_binB(const int* __restrict__ binCur, const unsigned* __restrict__ binned,
              int* __restrict__ off_all, unsigned short* __restrict__ rows)
{
    __shared__ int cntS[512];
    __shared__ int lcur[512];
    __shared__ int part[256];
    __shared__ int buf[BCAP];
    int rel = blockIdx.x / NBUCK;
    int bkt = blockIdx.x - rel * NBUCK;
    const unsigned* bn = binned + ((long)rel * NBUCK + bkt) * CAPREG;
    int* off = off_all + rel * (NN + 1);
    unsigned short* rw = rows + (long)rel * NE;
    int cnt = binCur[rel * NBUCK + bkt] - bkt * CAPREG;
    int gbase = 0;
    for (int b = 0; b < bkt; ++b) gbase += binCur[rel * NBUCK + b] - b * CAPREG;
    int nb0 = bkt << 9;
    int nb1 = min(nb0 + 512, NN);
    int nloc = nb1 - nb0;
    int tid = threadIdx.x;
    if (bkt == 0 && tid == 0) off[NN] = NE;

    cntS[tid] = 0; cntS[tid + 256] = 0;
    __syncthreads();
    for (int j = tid; j < cnt; j += 256) {
        int c = (int)(bn[j] >> 15);
        atomicAdd(&cntS[c - nb0], 1);
    }
    __syncthreads();
    int c0 = cntS[2 * tid], c1 = cntS[2 * tid + 1];
    part[tid] = c0 + c1;
    __syncthreads();
    for (int d = 1; d < 256; d <<= 1) {
        int u = (tid >= d) ? part[tid - d] : 0;
        __syncthreads();
        part[tid] += u;
        __syncthreads();
    }
    int pre = (tid == 0) ? 0 : part[tid - 1];
    cntS[2 * tid] = pre;
    cntS[2 * tid + 1] = pre + c0;
    __syncthreads();
    for (int i = tid; i < nloc; i += 256) off[nb0 + i] = gbase + cntS[i];
    lcur[tid] = cntS[tid]; lcur[tid + 256] = cntS[tid + 256];
    __syncthreads();
    if (cnt <= BCAP) {
        for (int j = tid; j < cnt; j += 256) {
            unsigned p = bn[j];
            int r = (int)(p & 0x7FFF);
            int c = (int)(p >> 15);
            int pos = atomicAdd(&lcur[c - nb0], 1);
            buf[pos] = r;
        }
        __syncthreads();
        for (int i = tid; i < cnt; i += 256) rw[gbase + i] = (unsigned short)buf[i];
    } else {
        for (int j = tid; j < cnt; j += 256) {
            unsigned p = bn[j];
            int r = (int)(p & 0x7FFF);
            int c = (int)(p >> 15);
            int pos = atomicAdd(&lcur[c - nb0], 1);
            rw[gbase + pos] = (unsigned short)r;
        }
    }
}

// ---------------- layer-1 attention dots (h1 in fp16) ----------------
__global__ __launch_bounds__(256)
void attn_dots1(const __half* __restrict__ h1h,
                const float* __restrict__ att_src,
                const float* __restrict__ att_dst,
                float* __restrict__ asrc, float* __restrict__ adst)
{
    int gid = blockIdx.x * 256 + threadIdx.x;
    int wave = gid >> 6;
    int lane = gid & 63;
    if (wave >= 4 * NN) return;
    int t = wave / NN;
    int n = wave - t * NN;
    __half2 hh = *(const __half2*)&h1h[(long)(t * NN + n) * 128 + 2 * lane];
    float2 hv = __half22float2(hh);
    const int SRCc[10] = {0,1,2,3,0,1,2,1,3,1};
    const int DSTc[10] = {0,1,2,3,1,0,1,2,1,3};
#pragma unroll
    for (int e = 0; e < 10; ++e) {
        if (SRCc[e] == t) {
            float2 av = *(const float2*)&att_src[e * 128 + 2 * lane];
            float p = hv.x * av.x + hv.y * av.y;
#pragma unroll
            for (int off = 1; off < 8; off <<= 1) p += __shfl_xor(p, off, 64);
            if ((lane & 7) == 0) asrc[(long)(e * NN + n) * 8 + (lane >> 3)] = p;
        }
        if (DSTc[e] == t) {
            float2 bv = *(const float2*)&att_dst[e * 128 + 2 * lane];
            float p = hv.x * bv.x + hv.y * bv.y;
#pragma unroll
            for (int off = 1; off < 8; off <<= 1) p += __shfl_xor(p, off, 64);
            if ((lane & 7) == 0) adst[(long)(e * NN + n) * 8 + (lane >> 3)] = p;
        }
    }
}

// ---------------- layer-1 gather-aggregate: XCD-pinned, phase-A prefetch ----------
// (round-11 proven-best form) Phase A: round of 8 edges, lane (eA,hA) computes one
// (edge,head) weight; next round's rows/asrc prefetched during FMA phase.
// Phase B: 4 edge-slots x 16 lanes x 8 channels (16B loads); shfl_xor(16,32).
__global__ __launch_bounds__(256)
void gather_agg1_all(const int* __restrict__ csr_off,
                     const unsigned short* __restrict__ csr_rows,
                     const float* __restrict__ asrc1, const float* __restrict__ adst1,
                     const __half* __restrict__ h1h, __half* __restrict__ slots16)
{
    int g = blockIdx.x;
    int xcd = g & 7;
    int slot = g >> 3;
    int e, i;
    if (slot < d_XCNTA[xcd]) { e = d_XRELA[xcd]; i = d_XBASEA[xcd] + slot; }
    else                     { e = d_XRELB[xcd]; i = slot - d_XCNTA[xcd]; }
    int node = i * 4 + (threadIdx.x >> 6);
    int lane = threadIdx.x & 63;
    if (node >= NN) return;
    const int* off = csr_off + e * (NN + 1);
    const unsigned short* rows = csr_rows + (long)e * NE;
    const float* asrc_e = asrc1 + (long)e * NN * 8;
    const float* adst_e = adst1 + (long)e * NN * 8;
    const _Float16* h1s = (const _Float16*)h1h + (long)d_SRC[e] * NN * 128;
    __half* out = slots16 + (long)e * NN * 128;

    const int g2  = lane >> 4;    // edge-slot (0..3)
    const int s16 = lane & 15;    // channel group: ch 8*s16 .. 8*s16+7
    const int hv  = s16 >> 1;     // head of those channels
    const int eA  = lane >> 3;    // phase-A edge
    const int hA  = lane & 7;     // phase-A head
    int beg = off[node], end = off[node + 1];
    float adA = adst_e[node * 8 + hA];
    float den = (g2 == 0) ? 1e-16f : 0.f;
    float a0 = 0.f, a1 = 0.f, a2 = 0.f, a3 = 0.f;
    float a4 = 0.f, a5 = 0.f, a6 = 0.f, a7 = 0.f;

#define GA1_STEP(i)                                                              \
    {                                                                            \
        int e0 = 4 * (i) + g2;                                                   \
        float wi = __shfl(w, e0 * 8 + hv, 64);                                   \
        int ri = __shfl(r, e0 * 8, 64);                                          \
        f16x8 v = *(const f16x8*)(h1s + (long)ri * 128 + 8 * s16);               \
        den += wi;                                                               \
        a0 += wi * (float)v[0]; a1 += wi * (float)v[1];                          \
        a2 += wi * (float)v[2]; a3 += wi * (float)v[3];                          \
        a4 += wi * (float)v[4]; a5 += wi * (float)v[5];                          \
        a6 += wi * (float)v[6]; a7 += wi * (float)v[7];                          \
    }

    if (beg < end) {
        int j0 = beg;
        int jj = j0 + eA;
        bool ok = jj < end;
        int r = (int)rows[ok ? jj : beg];
        float aw = asrc_e[r * 8 + hA] + adA;
        while (true) {
            float al = aw > 0.f ? aw : 0.2f * aw;
            float w = ok ? __expf(al) : 0.f;
            int j1 = j0 + 8;
            // prefetch next round's edge row + attention dot
            int rn = r; float awn = 0.f; bool okn = false;
            if (j1 < end) {
                int jn = j1 + eA;
                okn = jn < end;
                rn = (int)rows[okn ? jn : beg];
                awn = asrc_e[rn * 8 + hA] + adA;
            }
            int cnt = end - j0;
            GA1_STEP(0)
            if (cnt > 4) { GA1_STEP(1) }
            if (j1 >= end) break;
            j0 = j1; r = rn; aw = awn; ok = okn;
        }
    }
#undef GA1_STEP
#pragma unroll
    for (int m = 16; m < 64; m <<= 1) {
        a0 += __shfl_xor(a0, m, 64); a1 += __shfl_xor(a1, m, 64);
        a2 += __shfl_xor(a2, m, 64); a3 += __shfl_xor(a3, m, 64);
        a4 += __shfl_xor(a4, m, 64); a5 += __shfl_xor(a5, m, 64);
        a6 += __shfl_xor(a6, m, 64); a7 += __shfl_xor(a7, m, 64);
        den += __shfl_xor(den, m, 64);
    }
    if (g2 == 0) {
        float inv = 1.0f / den;
        f16x8 o;
        o[0] = (_Float16)(a0 * inv); o[1] = (_Float16)(a1 * inv);
        o[2] = (_Float16)(a2 * inv); o[3] = (_Float16)(a3 * inv);
        o[4] = (_Float16)(a4 * inv); o[5] = (_Float16)(a5 * inv);
        o[6] = (_Float16)(a6 * inv); o[7] = (_Float16)(a7 * inv);
        *(f16x8*)((_Float16*)out + (long)node * 128 + 8 * s16) = o;
    }
}

// ---------------- per-type fusion (batched): out = elu( sum sattn[e]*relu(slot_e) ) --
__global__ __launch_bounds__(256)
void fusion_all(const __half* __restrict__ slots16, const float* __restrict__ sattn,
                __half* __restrict__ h1f)
{
    int t = blockIdx.y;
    int idx = blockIdx.x * 256 + threadIdx.x;
    if (idx >= NN * 32) return;
    int c4 = idx & 31;
    int n = idx >> 5;
    long off = (long)n * 128 + c4 * 4;
    int cnt = d_FCNT[t];
    float o0 = 0.f, o1 = 0.f, o2 = 0.f, o3 = 0.f;
    for (int j = 0; j < cnt; ++j) {
        int e = d_FREL[t][j];
        float w = sattn[e];
        const __half* p = slots16 + (long)e * NN * 128 + off;
        float2 v01 = __half22float2(*(const __half2*)p);
        float2 v23 = __half22float2(*(const __half2*)(p + 2));
        o0 += w * fmaxf(v01.x, 0.f);
        o1 += w * fmaxf(v01.y, 0.f);
        o2 += w * fmaxf(v23.x, 0.f);
        o3 += w * fmaxf(v23.y, 0.f);
    }
    o0 = o0 > 0.f ? o0 : __expf(o0) - 1.f;
    o1 = o1 > 0.f ? o1 : __expf(o1) - 1.f;
    o2 = o2 > 0.f ? o2 : __expf(o2) - 1.f;
    o3 = o3 > 0.f ? o3 : __expf(o3) - 1.f;
    __half* q = h1f + (long)t * NN * 128 + off;
    *(__half2*)q = __floats2half2_rn(o0, o1);
    *(__half2*)(q + 2) = __floats2half2_rn(o2, o3);
}

// ---------------- layer-2 attention dots (h2 in fp16; 1 head, 32 ch) --------------
__global__ __launch_bounds__(256)
void attn_dots2(const __half* __restrict__ h2h,
                const float* __restrict__ att_src,
                const float* __restrict__ att_dst,
                float* __restrict__ asrc, float* __restrict__ adst)
{
    int gid = blockIdx.x * 256 + threadIdx.x;
    int p = gid >> 5;
    int l = gid & 31;
    if (p >= 10 * NN) return;
    int e = p / NN, n = p - e * NN;
    int s = d_SRC[e], d = d_DST[e];
    float hs = __half2float(h2h[(long)(s * NN + n) * 32 + l]);
    float hd = __half2float(h2h[(long)(d * NN + n) * 32 + l]);
    float ps = hs * att_src[e * 32 + l];
    float pd = hd * att_dst[e * 32 + l];
#pragma unroll
    for (int off = 1; off < 32; off <<= 1) {
        ps += __shfl_xor(ps, off, 64);
        pd += __shfl_xor(pd, off, 64);
    }
    if (l == 0) { asrc[e * NN + n] = ps; adst[e * NN + n] = pd; }
}

// ---------------- layer-2 gather-aggregate: 32 lanes/node, 4 edge-slots ----------
__global__ __launch_bounds__(256)
void gather_agg2(const int* __restrict__ csr_off,
                 const unsigned short* __restrict__ csr_rows,
                 const __half* __restrict__ h2h,
                 const float* __restrict__ asrc, const float* __restrict__ adst,
                 __half* __restrict__ agg2h)
{
    int e = d_RORD[blockIdx.y];
    int node = blockIdx.x * 8 + (threadIdx.x >> 5);
    int lane = threadIdx.x & 31;
    if (node >= NN) return;
    const int* off = csr_off + e * (NN + 1);
    const unsigned short* rows = csr_rows + (long)e * NE;
    const __half* h2s = h2h + (long)d_SRC[e] * NN * 32;
    const float* as = asrc + e * NN;
    const int slot = lane >> 3;   // edge-slot (0..3)
    const int sub = lane & 7;     // channel group: channels 4*sub .. 4*sub+3
    float ad = adst[e * NN + node];
    int beg = off[node], end = off[node + 1];
    float den = (slot == 0) ? 1e-16f : 0.f;
    float a0 = 0.f, a1 = 0.f, a2 = 0.f, a3 = 0.f;

#define GA2_STEP(i)                                                              \
    {                                                                            \
        int e0 = (i) * 4 + slot;                                                 \
        float wi = __shfl(w, e0, 32);                                            \
        int ri = __shfl(r, e0, 32);                                              \
        h2x2 v = *(const h2x2*)(h2s + (long)ri * 32 + 4 * sub);                  \
        float2 f0 = __half22float2(v.a);                                         \
        float2 f1 = __half22float2(v.b);                                         \
        den += wi;                                                               \
        a0 += wi * f0.x; a1 += wi * f0.y; a2 += wi * f1.x; a3 += wi * f1.y;      \
    }

    for (int j0 = beg; j0 < end; j0 += 32) {
        int jj = j0 + lane;
        bool ok = jj < end;
        int r = (int)rows[ok ? jj : beg];
        float a = as[r] + ad;
        a = a > 0.f ? a : 0.2f * a;
        float w = ok ? __expf(a) : 0.f;
        int cnt = end - j0;
        if (cnt >= 32) {
            GA2_STEP(0) GA2_STEP(1) GA2_STEP(2) GA2_STEP(3)
            GA2_STEP(4) GA2_STEP(5) GA2_STEP(6) GA2_STEP(7)
        } else {
            int it = (cnt + 3) >> 2;
            for (int i = 0; i < it; ++i) GA2_STEP(i)
        }
    }
#undef GA2_STEP
#pragma unroll
    for (int m = 8; m < 32; m <<= 1) {
        a0 += __shfl_xor(a0, m, 32);
        a1 += __shfl_xor(a1, m, 32);
        a2 += __shfl_xor(a2, m, 32);
        a3 += __shfl_xor(a3, m, 32);
        den += __shfl_xor(den, m, 32);
    }
    if (slot == 0) {
        float inv = 1.0f / den;
        h2x2 o;
        o.a = __floats2half2_rn(a0 * inv, a1 * inv);
        o.b = __floats2half2_rn(a2 * inv, a3 * inv);
        *(h2x2*)(agg2h + ((long)e * NN + node) * 32 + 4 * sub) = o;
    }
}

// ---------------- semantic score + softmax over ALL types ----------------
__global__ void score_all_k(const float* __restrict__ colsum, const float* __restrict__ q,
                            float* __restrict__ sattn, int C)
{
    __shared__ float sc[10];
    int tid = threadIdx.x;
    if (tid < 10) {
        float s = 0.f;
        for (int c = 0; c < C; ++c) s += q[c] * colsum[tid * C + c];
        sc[tid] = s / (float)NN;
    }
    __syncthreads();
    if (tid < 4) {
        float mx = -1e30f;
        for (int m = 0; m < 10; ++m) if (d_DST[m] == tid) mx = fmaxf(mx, sc[m]);
        float ex[10];
        float sum = 0.f;
        for (int m = 0; m < 10; ++m) {
            ex[m] = 0.f;
            if (d_DST[m] == tid) { ex[m] = __expf(sc[m] - mx); sum += ex[m]; }
        }
        for (int m = 0; m < 10; ++m) if (d_DST[m] == tid) sattn[m] = ex[m] / sum;
    }
}

// ---------------- final: per-node channel softmax, fp16 agg in, fp32 out ----------
__global__ __launch_bounds__(256)
void final_softmax(const __half* __restrict__ agg, const float* __restrict__ sattn,
                   float* __restrict__ out)
{
    int gid = blockIdx.x * 256 + threadIdx.x;
    int c = gid & 31;
    int p = gid >> 5;
    if (p >= 4 * NN) return;
    int t = p / NN, n = p - t * NN;
    float f = 0.f;
    for (int m = 0; m < 10; ++m) {
        if (d_DST[m] != t) continue;
        f += sattn[m] * fmaxf(__half2float(agg[(long)(m * NN + n) * 32 + c]), 0.f);
    }
    float mx = f;
#pragma unroll
    for (int off = 1; off < 32; off <<= 1) mx = fmaxf(mx, __shfl_xor(mx, off, 64));
    float ex = __expf(f - mx);
    float sm = ex;
#pragma unroll
    for (int off = 1; off < 32; off <<= 1) sm += __shfl_xor(sm, off, 64);
    out[(long)(t * NN + n) * 32 + c] = ex / sm;
}

extern "C" void kernel_launch(void* const* d_in, const int* in_sizes, int n_in,
                              void* d_out, int out_size, void* d_ws, size_t ws_size,
                              hipStream_t stream) {
    const float* x[4] = {
        (const float*)d_in[0], (const float*)d_in[1],
        (const float*)d_in[2], (const float*)d_in[3]};
    const int* edges = (const int*)d_in[4];
    const float* W1    = (const float*)d_in[5];
    const float* b1    = (const float*)d_in[6];
    const float* att1s = (const float*)d_in[7];
    const float* att1d = (const float*)d_in[8];
    const float* k1W   = (const float*)d_in[9];
    const float* k1b   = (const float*)d_in[10];
    const float* q1    = (const float*)d_in[11];
    const float* W2    = (const float*)d_in[12];
    const float* b2    = (const float*)d_in[13];
    const float* att2s = (const float*)d_in[14];
    const float* att2d = (const float*)d_in[15];
    const float* k2W   = (const float*)d_in[16];
    const float* k2b   = (const float*)d_in[17];
    const float* q2    = (const float*)d_in[18];

    // ---- workspace layout (floats), peak ~170 MB ----
    float* W = (float*)d_ws;
    // region 0 [0, 15.36M floats):
    //   layer 1: h1h fp16 [4][NN][128]; after fusion: h1f overlays 0, h2h at 7.68M
    __half* h1h    = (__half*)W;
    __half* h1f    = (__half*)W;
    __half* h2h    = (__half*)(W + 7680000);
    // slots region [15.36M, 34.56M): slots16 fp16 [10][NN][128];
    //   CSR binned scratch overlays it before the gathers; agg2h overlays after fusion.
    __half* slots16 = (__half*)(W + 15360000);
    __half* agg2h  = (__half*)(W + 15360000);  // [10][NN][32] fp16 (slots16 dead)
    unsigned* binned = (unsigned*)(W + 15360000); // 10*59*12288 u32
    int*   binCur  = (int*)(W + 15360000 + 7249920);
    float* asrc1   = W + 34560000;           // 2.4M
    float* adst1   = W + 36960000;           // 2.4M (asrc2/adst2 overlay after layer 1)
    float* asrc2   = W + 36960000;           // 0.3M
    float* adst2   = W + 37260000;           // 0.3M
    float* colsum1 = W + 39360000;           // 1,280
    float* sattn1  = W + 39361280;           // 16
    float* colsum2 = W + 39361296;           // 320
    float* sattn2  = W + 39361616;           // 16
    int*   csr_off = (int*)(W + 39361640);   // 300,010 ints
    unsigned short* csr_row = (unsigned short*)(csr_off + 300016); // 4,000,000 u16

    // ---- CSR build (3 dispatches; bucket prefix folded into binB) ----
    init_k<<<7, 256, 0, stream>>>(binCur, colsum1);
    csr_binA<<<BPR * 10, 256, 0, stream>>>(edges, binCur, binned);
    csr_binB<<<NBUCK * 10, 256, 0, stream>>>(binCur, binned, csr_off, csr_row);

    // layer-1 projection: ONE dispatch, BN=128 (A read once)
    proj1_k<<<dim3(235, 1, 4), 256, 0, stream>>>(
        x[0], x[1], x[2], x[3], W1, b1, h1h);

    attn_dots1<<<30000, 256, 0, stream>>>(h1h, att1s, att1d, asrc1, adst1);

    // ALL 10 relation gathers, ONE dispatch, XCD-pinned (1D grid = 8 x 9375)
    gather_agg1_all<<<75000, 256, 0, stream>>>(
        csr_off, csr_row, asrc1, adst1, h1h, slots16);

    // batched colsum over all 10 relations (fp16 A, BN=128: A read once)
    mgemm_k<128><<<dim3(235, 1, 10), 256, 0, stream>>>(
        (const _Float16*)slots16, (long)NN * 128, k1W, 0, k1b, 0,
        colsum1, 128, NN, 128, 128, 1, 1);
    score_all_k<<<1, 64, 0, stream>>>(colsum1, q1, sattn1, 128);

    // batched fusion over 4 dst types -> h1f fp16
    fusion_all<<<dim3(3750, 4), 256, 0, stream>>>(slots16, sattn1, h1f);

    // layer-2 projection (batched z=4, fp16 A): h2h[t] = fp16( h1f[t] @ W2[t] + b2[t] )
    mgemm_k<32><<<dim3(235, 1, 4), 256, 0, stream>>>(
        (const _Float16*)h1f, (long)NN * 128, W2, 128L * 32, b2, 32,
        (float*)h2h, (long)NN * 16, NN, 128, 32, 0, 2);

    attn_dots2<<<37500, 256, 0, stream>>>(h2h, att2s, att2d, asrc2, adst2);
    gather_agg2<<<dim3(3750, 10), 256, 0, stream>>>(
        csr_off, csr_row, h2h, asrc2, adst2, agg2h);

    // batched colsum over all 10 relations (fp16 A)
    mgemm_k<32><<<dim3(235, 1, 10), 256, 0, stream>>>(
        (const _Float16*)agg2h, (long)NN * 32, k2W, 0, k2b, 0,
        colsum2, 32L, NN, 32, 32, 1, 1);
    score_all_k<<<1, 64, 0, stream>>>(colsum2, q2, sattn2, 32);
    final_softmax<<<15000, 256, 0, stream>>>(agg2h, sattn2, (float*)d_out);
}

// Round 14
// 710.985 us; speedup vs baseline: 1.0588x; 1.0588x over previous
//
#include <hip/hip_runtime.h>
#include <hip/hip_fp16.h>

#define NN 30000
#define NE 400000
#define NBUCK 59     // ceil(30000/512)
#define BPR 98       // blocks per relation in csr_binA: ceil(400000/4096)
#define EPB 4096     // edges per block in csr_binA
#define CAPREG 12288 // fixed slots per (rel,bucket) in binned scratch (mean 6827, sigma 82)
#define BCAP 12288   // LDS sort capacity in csr_binB

__constant__ int d_SRC[10] = {0,1,2,3,0,1,2,1,3,1};
__constant__ int d_DST[10] = {0,1,2,3,1,0,1,2,1,3};
// gather_agg2 relation order grouped by src type (L2 slice reuse)
__constant__ int d_RORD[10] = {1,5,7,9,0,4,2,6,3,8};
// fusion tables: per dst type, relations ending there
__constant__ int d_FCNT[4] = {2,4,2,2};
__constant__ int d_FREL[4][4] = {{0,5,0,0},{1,4,6,8},{2,7,0,0},{3,9,0,0}};

// XCD-pinned schedule for gather_agg1_all: block g -> xcd = g%8 (HW round-robin),
// slot = g/8 in [0,9375). Each XCD serves at most 2 relations.
__constant__ int d_XRELA[8]  = {0,4,2,6,8,1,5,7};
__constant__ int d_XBASEA[8] = {0,1875,3750,5625,0,1875,3750,5625};
__constant__ int d_XCNTA[8]  = {7500,5625,3750,1875,7500,5625,3750,1875};
__constant__ int d_XRELB[8]  = {4,2,6,3,1,5,7,9};

typedef _Float16 f16x8 __attribute__((ext_vector_type(8)));
typedef float f32x4 __attribute__((ext_vector_type(4)));

struct __attribute__((aligned(8))) h2x2 { __half2 a, b; };

// ---------------- layer-1 projection: 4 node types, ONE dispatch (z selects x) ----
// BM=128, BK=32, BN=64 (measured-best shape); fp32 A -> fp16 staging; fp16 store.
__global__ __launch_bounds__(256)
void proj1_k(const float* __restrict__ A0, const float* __restrict__ A1,
             const float* __restrict__ A2, const float* __restrict__ A3,
             const float* __restrict__ B, const float* __restrict__ bias,
             __half* __restrict__ C)
{
    constexpr int BM = 128, BK = 32, MR = 2, NF = 4, LDK = BK + 8;
    constexpr int K = 256, N = 128, M = NN;
    const int z = blockIdx.z;
    const float* A = (z == 0) ? A0 : (z == 1) ? A1 : (z == 2) ? A2 : A3;
    const float* Bz = B + (long)z * K * N;
    const float* bz = bias + z * N;
    __half* Cz = C + (long)z * M * N;
    const int m0 = blockIdx.x * BM;
    const int n0 = blockIdx.y * 64;
    const int tid = threadIdx.x;
    const int wv = tid >> 6;
    const int l  = tid & 63;
    const int fm = l & 15;
    const int fg = l >> 4;

    __shared__ _Float16 As[BM][LDK];
    __shared__ _Float16 Bs[64][LDK];

    f32x4 acc[MR][NF];
#pragma unroll
    for (int mr = 0; mr < MR; ++mr)
#pragma unroll
        for (int f = 0; f < NF; ++f) acc[mr][f] = (f32x4){0.f, 0.f, 0.f, 0.f};

    const int arow = tid >> 1;
    const int akc  = (tid & 1) << 4;
    const int grow = m0 + arow;

    for (int k0 = 0; k0 < K; k0 += BK) {
        f16x8 ap0, ap1;
        if (grow < M) {
            const float* aq = A + (long)grow * K + k0 + akc;
            float4 u0 = *(const float4*)aq;
            float4 u1 = *(const float4*)(aq + 4);
            float4 u2 = *(const float4*)(aq + 8);
            float4 u3 = *(const float4*)(aq + 12);
            float v[16] = {u0.x,u0.y,u0.z,u0.w, u1.x,u1.y,u1.z,u1.w,
                           u2.x,u2.y,u2.z,u2.w, u3.x,u3.y,u3.z,u3.w};
#pragma unroll
            for (int j = 0; j < 8; ++j) { ap0[j] = (_Float16)v[j]; ap1[j] = (_Float16)v[j+8]; }
        } else {
#pragma unroll
            for (int j = 0; j < 8; ++j) { ap0[j] = (_Float16)0.f; ap1[j] = (_Float16)0.f; }
        }
        *(f16x8*)&As[arow][akc]     = ap0;
        *(f16x8*)&As[arow][akc + 8] = ap1;

        {
            const int bk = tid >> 4;
            const int bn = (tid & 15) << 2;
#pragma unroll
            for (int kk = 0; kk < 2; ++kk) {
                int kr = bk + kk * 16;
                float4 u = *(const float4*)(Bz + (long)(k0 + kr) * N + n0 + bn);
                Bs[bn + 0][kr] = (_Float16)u.x;
                Bs[bn + 1][kr] = (_Float16)u.y;
                Bs[bn + 2][kr] = (_Float16)u.z;
                Bs[bn + 3][kr] = (_Float16)u.w;
            }
        }
        __syncthreads();

        f16x8 a0 = *(const f16x8*)&As[wv * 32 + fm][fg * 8];
        f16x8 a1 = *(const f16x8*)&As[wv * 32 + 16 + fm][fg * 8];
#pragma unroll
        for (int f = 0; f < NF; ++f) {
            f16x8 b = *(const f16x8*)&Bs[f * 16 + fm][fg * 8];
            acc[0][f] = __builtin_amdgcn_mfma_f32_16x16x32_f16(a0, b, acc[0][f], 0, 0, 0);
            acc[1][f] = __builtin_amdgcn_mfma_f32_16x16x32_f16(a1, b, acc[1][f], 0, 0, 0);
        }
        __syncthreads();
    }

#pragma unroll
    for (int f = 0; f < NF; ++f) {
        float bzv = bz[n0 + f * 16 + fm];
#pragma unroll
        for (int mr = 0; mr < MR; ++mr)
#pragma unroll
            for (int i = 0; i < 4; ++i) {
                int gr = m0 + wv * 32 + mr * 16 + fg * 4 + i;
                if (gr < M) Cz[(long)gr * N + n0 + f * 16 + fm] = __float2half(acc[mr][f][i] + bzv);
            }
    }
}

// ---------------- MFMA GEMM (fp16 A): C[M,N] = act(A)[M,K] @ B[K,N] + bias ----
// BN in {64, 32}. epi=1: tanh + column-sum -> atomicAdd C[N]. epi=2: store fp16.
template<int BN>
__global__ __launch_bounds__(256)
void mgemm_k(const _Float16* __restrict__ Ah, long sA,
             const float* __restrict__ B, long sB,
             const float* __restrict__ bias, long sBias,
             float* __restrict__ C, long sC,
             int M, int K, int N, int relu_a, int epi)
{
    constexpr int BM = 128, BK = 32, MR = 2;
    constexpr int NF = BN / 16;
    constexpr int LDK = BK + 8;
    const int z = blockIdx.z;
    Ah += (long)z * sA;
    B += (long)z * sB;
    bias += (long)z * sBias;
    C += (long)z * sC;
    const int m0 = blockIdx.x * BM;
    const int n0 = blockIdx.y * BN;
    const int tid = threadIdx.x;
    const int wv = tid >> 6;
    const int l  = tid & 63;
    const int fm = l & 15;
    const int fg = l >> 4;

    __shared__ _Float16 As[BM][LDK];
    __shared__ _Float16 Bs[BN][LDK];
    __shared__ float red[4][BN];

    f32x4 acc[MR][NF];
#pragma unroll
    for (int mr = 0; mr < MR; ++mr)
#pragma unroll
        for (int f = 0; f < NF; ++f) acc[mr][f] = (f32x4){0.f, 0.f, 0.f, 0.f};

    const int arow = tid >> 1;
    const int akc  = (tid & 1) << 4;
    const int grow = m0 + arow;

    for (int k0 = 0; k0 < K; k0 += BK) {
        f16x8 ap0, ap1;
        if (grow < M) {
            const _Float16* aq = Ah + (long)grow * K + k0 + akc;
            ap0 = *(const f16x8*)aq;
            ap1 = *(const f16x8*)(aq + 8);
            if (relu_a) {
#pragma unroll
                for (int j = 0; j < 8; ++j) {
                    ap0[j] = ap0[j] > (_Float16)0.f ? ap0[j] : (_Float16)0.f;
                    ap1[j] = ap1[j] > (_Float16)0.f ? ap1[j] : (_Float16)0.f;
                }
            }
        } else {
#pragma unroll
            for (int j = 0; j < 8; ++j) { ap0[j] = (_Float16)0.f; ap1[j] = (_Float16)0.f; }
        }
        *(f16x8*)&As[arow][akc]     = ap0;
        *(f16x8*)&As[arow][akc + 8] = ap1;

        if constexpr (BN == 64) {
            const int bk = tid >> 4;
            const int bn = (tid & 15) << 2;
#pragma unroll
            for (int kk = 0; kk < 2; ++kk) {
                int kr = bk + kk * 16;
                float4 u = *(const float4*)(B + (long)(k0 + kr) * N + n0 + bn);
                Bs[bn + 0][kr] = (_Float16)u.x;
                Bs[bn + 1][kr] = (_Float16)u.y;
                Bs[bn + 2][kr] = (_Float16)u.z;
                Bs[bn + 3][kr] = (_Float16)u.w;
            }
        } else {                                 // BN == 32
            const int bk = tid >> 3;
            const int bn = (tid & 7) << 2;
            float4 u = *(const float4*)(B + (long)(k0 + bk) * N + n0 + bn);
            Bs[bn + 0][bk] = (_Float16)u.x;
            Bs[bn + 1][bk] = (_Float16)u.y;
            Bs[bn + 2][bk] = (_Float16)u.z;
            Bs[bn + 3][bk] = (_Float16)u.w;
        }
        __syncthreads();

        f16x8 a0 = *(const f16x8*)&As[wv * 32 + fm][fg * 8];
        f16x8 a1 = *(const f16x8*)&As[wv * 32 + 16 + fm][fg * 8];
#pragma unroll
        for (int f = 0; f < NF; ++f) {
            f16x8 b = *(const f16x8*)&Bs[f * 16 + fm][fg * 8];
            acc[0][f] = __builtin_amdgcn_mfma_f32_16x16x32_f16(a0, b, acc[0][f], 0, 0, 0);
            acc[1][f] = __builtin_amdgcn_mfma_f32_16x16x32_f16(a1, b, acc[1][f], 0, 0, 0);
        }
        __syncthreads();
    }

    if (epi == 2) {
        __half* Ch = (__half*)C;
#pragma unroll
        for (int f = 0; f < NF; ++f) {
            float bz = bias[n0 + f * 16 + fm];
#pragma unroll
            for (int mr = 0; mr < MR; ++mr)
#pragma unroll
                for (int i = 0; i < 4; ++i) {
                    int gr = m0 + wv * 32 + mr * 16 + fg * 4 + i;
                    if (gr < M) Ch[(long)gr * N + n0 + f * 16 + fm] = __float2half(acc[mr][f][i] + bz);
                }
        }
    } else {
#pragma unroll
        for (int f = 0; f < NF; ++f) {
            float bz = bias[n0 + f * 16 + fm];
            float s = 0.f;
#pragma unroll
            for (int mr = 0; mr < MR; ++mr)
#pragma unroll
                for (int i = 0; i < 4; ++i) {
                    int gr = m0 + wv * 32 + mr * 16 + fg * 4 + i;
                    if (gr < M) s += tanhf(acc[mr][f][i] + bz);
                }
            s += __shfl_xor(s, 16, 64);
            s += __shfl_xor(s, 32, 64);
            if (fg == 0) red[wv][f * 16 + fm] = s;
        }
        __syncthreads();
        if (tid < BN) {
            float s = red[0][tid] + red[1][tid] + red[2][tid] + red[3][tid];
            unsafeAtomicAdd(&C[n0 + tid], s);
        }
    }
}

// ---------------- init: bucket cursors + colsum zeroing ----------------
__global__ __launch_bounds__(256)
void init_k(int* __restrict__ binCur, float* __restrict__ colsum)
{
    int i = blockIdx.x * 256 + threadIdx.x;
    if (i < 10 * NBUCK) binCur[i] = (i % NBUCK) * CAPREG;
    if (i < 1632) colsum[i] = 0.f;
}

__global__ __launch_bounds__(256)
void csr_binA(const int* __restrict__ edges, int* __restrict__ binCur,
              unsigned* __restrict__ binned)
{
    __shared__ int lcnt[NBUCK];
    __shared__ int gbase[NBUCK];
    int rel = blockIdx.x / BPR;
    int blk = blockIdx.x - rel * BPR;
    int base = blk * EPB;
    int tid = threadIdx.x;
    for (int b = tid; b < NBUCK; b += 256) lcnt[b] = 0;
    __syncthreads();
    const int* er = edges + (long)rel * 2 * NE;
    const int* ec = er + NE;
    unsigned pk[16];
    unsigned mt[16];
#pragma unroll
    for (int k = 0; k < 16; ++k) {
        int i = base + k * 256 + tid;
        if (i < NE) {
            int r = er[i];
            int c = ec[i];
            int b = c >> 9;
            int lo = atomicAdd(&lcnt[b], 1);
            pk[k] = ((unsigned)c << 15) | (unsigned)r;
            mt[k] = ((unsigned)b << 16) | (unsigned)lo;
        } else {
            mt[k] = 0xFFFFFFFFu;
        }
    }
    __syncthreads();
    if (tid < NBUCK) gbase[tid] = atomicAdd(&binCur[rel * NBUCK + tid], lcnt[tid]);
    __syncthreads();
    unsigned* bn = binned + (long)rel * NBUCK * CAPREG;
#pragma unroll
    for (int k = 0; k < 16; ++k) {
        if (mt[k] != 0xFFFFFFFFu) {
            int b = mt[k] >> 16;
            int lo = mt[k] & 0xFFFF;
            bn[gbase[b] + lo] = pk[k];
        }
    }
}

// Pass B: per (rel,bucket) block: per-node histogram + scan -> csr_off segment;
// LDS sort; coalesced stream-out (u16 rows). Bucket CSR base computed inline.
__global__ __launch_bounds__(256)
void csr_binB(const int* __restrict__ binCur, const unsigned* __restrict__ binned,
              int* __restrict__ off_all, unsigned short* __restrict__ rows)
{
    __shared__ int cntS[512];
    __shared__ int lcur[512];
    __shared__ int part[256];
    __shared__ int buf[BCAP];
    int rel = blockIdx.x / NBUCK;
    int bkt = blockIdx.x - rel * NBUCK;
    const unsigned* bn = binned + ((long)rel * NBUCK + bkt) * CAPREG;
    int* off = off_all + rel * (NN + 1);
    unsigned short* rw = rows + (long)rel * NE;
    int cnt = binCur[rel * NBUCK + bkt] - bkt * CAPREG;
    int gbase = 0;
    for (int b = 0; b < bkt; ++b) gbase += binCur[rel * NBUCK + b] - b * CAPREG;
    int nb0 = bkt << 9;
    int nb1 = min(nb0 + 512, NN);
    int nloc = nb1 - nb0;
    int tid = threadIdx.x;
    if (bkt == 0 && tid == 0) off[NN] = NE;

    cntS[tid] = 0; cntS[tid + 256] = 0;
    __syncthreads();
    for (int j = tid; j < cnt; j += 256) {
        int c = (int)(bn[j] >> 15);
        atomicAdd(&cntS[c - nb0], 1);
    }
    __syncthreads();
    int c0 = cntS[2 * tid], c1 = cntS[2 * tid + 1];
    part[tid] = c0 + c1;
    __syncthreads();
    for (int d = 1; d < 256; d <<= 1) {
        int u = (tid >= d) ? part[tid - d] : 0;
        __syncthreads();
        part[tid] += u;
        __syncthreads();
    }
    int pre = (tid == 0) ? 0 : part[tid - 1];
    cntS[2 * tid] = pre;
    cntS[2 * tid + 1] = pre + c0;
    __syncthreads();
    for (int i = tid; i < nloc; i += 256) off[nb0 + i] = gbase + cntS[i];
    lcur[tid] = cntS[tid]; lcur[tid + 256] = cntS[tid + 256];
    __syncthreads();
    if (cnt <= BCAP) {
        for (int j = tid; j < cnt; j += 256) {
            unsigned p = bn[j];
            int r = (int)(p & 0x7FFF);
            int c = (int)(p >> 15);
            int pos = atomicAdd(&lcur[c - nb0], 1);
            buf[pos] = r;
        }
        __syncthreads();
        for (int i = tid; i < cnt; i += 256) rw[gbase + i] = (unsigned short)buf[i];
    } else {
        for (int j = tid; j < cnt; j += 256) {
            unsigned p = bn[j];
            int r = (int)(p & 0x7FFF);
            int c = (int)(p >> 15);
            int pos = atomicAdd(&lcur[c - nb0], 1);
            rw[gbase + pos] = (unsigned short)r;
        }
    }
}

// ---------------- layer-1 attention dots (h1 in fp16) ----------------
__global__ __launch_bounds__(256)
void attn_dots1(const __half* __restrict__ h1h,
                const float* __restrict__ att_src,
                const float* __restrict__ att_dst,
                float* __restrict__ asrc, float* __restrict__ adst)
{
    int gid = blockIdx.x * 256 + threadIdx.x;
    int wave = gid >> 6;
    int lane = gid & 63;
    if (wave >= 4 * NN) return;
    int t = wave / NN;
    int n = wave - t * NN;
    __half2 hh = *(const __half2*)&h1h[(long)(t * NN + n) * 128 + 2 * lane];
    float2 hv = __half22float2(hh);
    const int SRCc[10] = {0,1,2,3,0,1,2,1,3,1};
    const int DSTc[10] = {0,1,2,3,1,0,1,2,1,3};
#pragma unroll
    for (int e = 0; e < 10; ++e) {
        if (SRCc[e] == t) {
            float2 av = *(const float2*)&att_src[e * 128 + 2 * lane];
            float p = hv.x * av.x + hv.y * av.y;
#pragma unroll
            for (int off = 1; off < 8; off <<= 1) p += __shfl_xor(p, off, 64);
            if ((lane & 7) == 0) asrc[(long)(e * NN + n) * 8 + (lane >> 3)] = p;
        }
        if (DSTc[e] == t) {
            float2 bv = *(const float2*)&att_dst[e * 128 + 2 * lane];
            float p = hv.x * bv.x + hv.y * bv.y;
#pragma unroll
            for (int off = 1; off < 8; off <<= 1) p += __shfl_xor(p, off, 64);
            if ((lane & 7) == 0) adst[(long)(e * NN + n) * 8 + (lane >> 3)] = p;
        }
    }
}

// ---------------- layer-1 gather-aggregate: XCD-pinned, phase-A prefetch ----------
// Phase A: round of 8 edges, lane (eA,hA) computes one (edge,head) weight; next
// round's rows/asrc prefetched during FMA phase.
// Phase B: 4 edge-slots x 16 lanes x 8 channels (16B loads); shfl_xor(16,32).
__global__ __launch_bounds__(256)
void gather_agg1_all(const int* __restrict__ csr_off,
                     const unsigned short* __restrict__ csr_rows,
                     const float* __restrict__ asrc1, const float* __restrict__ adst1,
                     const __half* __restrict__ h1h, __half* __restrict__ slots16)
{
    int g = blockIdx.x;
    int xcd = g & 7;
    int slot = g >> 3;
    int e, i;
    if (slot < d_XCNTA[xcd]) { e = d_XRELA[xcd]; i = d_XBASEA[xcd] + slot; }
    else                     { e = d_XRELB[xcd]; i = slot - d_XCNTA[xcd]; }
    int node = i * 4 + (threadIdx.x >> 6);
    int lane = threadIdx.x & 63;
    if (node >= NN) return;
    const int* off = csr_off + e * (NN + 1);
    const unsigned short* rows = csr_rows + (long)e * NE;
    const float* asrc_e = asrc1 + (long)e * NN * 8;
    const float* adst_e = adst1 + (long)e * NN * 8;
    const _Float16* h1s = (const _Float16*)h1h + (long)d_SRC[e] * NN * 128;
    __half* out = slots16 + (long)e * NN * 128;

    const int g2  = lane >> 4;    // edge-slot (0..3)
    const int s16 = lane & 15;    // channel group: ch 8*s16 .. 8*s16+7
    const int hv  = s16 >> 1;     // head of those channels
    const int eA  = lane >> 3;    // phase-A edge
    const int hA  = lane & 7;     // phase-A head
    int beg = off[node], end = off[node + 1];
    float adA = adst_e[node * 8 + hA];
    float den = (g2 == 0) ? 1e-16f : 0.f;
    float a0 = 0.f, a1 = 0.f, a2 = 0.f, a3 = 0.f;
    float a4 = 0.f, a5 = 0.f, a6 = 0.f, a7 = 0.f;

#define GA1_STEP(i)                                                              \
    {                                                                            \
        int e0 = 4 * (i) + g2;                                                   \
        float wi = __shfl(w, e0 * 8 + hv, 64);                                   \
        int ri = __shfl(r, e0 * 8, 64);                                          \
        f16x8 v = *(const f16x8*)(h1s + (long)ri * 128 + 8 * s16);               \
        den += wi;                                                               \
        a0 += wi * (float)v[0]; a1 += wi * (float)v[1];                          \
        a2 += wi * (float)v[2]; a3 += wi * (float)v[3];                          \
        a4 += wi * (float)v[4]; a5 += wi * (float)v[5];                          \
        a6 += wi * (float)v[6]; a7 += wi * (float)v[7];                          \
    }

    if (beg < end) {
        int j0 = beg;
        int jj = j0 + eA;
        bool ok = jj < end;
        int r = (int)rows[ok ? jj : beg];
        float aw = asrc_e[r * 8 + hA] + adA;
        while (true) {
            float al = aw > 0.f ? aw : 0.2f * aw;
            float w = ok ? __expf(al) : 0.f;
            int j1 = j0 + 8;
            // prefetch next round's edge row + attention dot
            int rn = r; float awn = 0.f; bool okn = false;
            if (j1 < end) {
                int jn = j1 + eA;
                okn = jn < end;
                rn = (int)rows[okn ? jn : beg];
                awn = asrc_e[rn * 8 + hA] + adA;
            }
            int cnt = end - j0;
            GA1_STEP(0)
            if (cnt > 4) { GA1_STEP(1) }
            if (j1 >= end) break;
            j0 = j1; r = rn; aw = awn; ok = okn;
        }
    }
#undef GA1_STEP
#pragma unroll
    for (int m = 16; m < 64; m <<= 1) {
        a0 += __shfl_xor(a0, m, 64); a1 += __shfl_xor(a1, m, 64);
        a2 += __shfl_xor(a2, m, 64); a3 += __shfl_xor(a3, m, 64);
        a4 += __shfl_xor(a4, m, 64); a5 += __shfl_xor(a5, m, 64);
        a6 += __shfl_xor(a6, m, 64); a7 += __shfl_xor(a7, m, 64);
        den += __shfl_xor(den, m, 64);
    }
    if (g2 == 0) {
        float inv = 1.0f / den;
        f16x8 o;
        o[0] = (_Float16)(a0 * inv); o[1] = (_Float16)(a1 * inv);
        o[2] = (_Float16)(a2 * inv); o[3] = (_Float16)(a3 * inv);
        o[4] = (_Float16)(a4 * inv); o[5] = (_Float16)(a5 * inv);
        o[6] = (_Float16)(a6 * inv); o[7] = (_Float16)(a7 * inv);
        *(f16x8*)((_Float16*)out + (long)node * 128 + 8 * s16) = o;
    }
}

// ---------------- per-type fusion (batched): out = elu( sum sattn[e]*relu(slot_e) ) --
__global__ __launch_bounds__(256)
void fusion_all(const __half* __restrict__ slots16, const float* __restrict__ sattn,
                __half* __restrict__ h1f)
{
    int t = blockIdx.y;
    int idx = blockIdx.x * 256 + threadIdx.x;
    if (idx >= NN * 32) return;
    int c4 = idx & 31;
    int n = idx >> 5;
    long off = (long)n * 128 + c4 * 4;
    int cnt = d_FCNT[t];
    float o0 = 0.f, o1 = 0.f, o2 = 0.f, o3 = 0.f;
    for (int j = 0; j < cnt; ++j) {
        int e = d_FREL[t][j];
        float w = sattn[e];
        const __half* p = slots16 + (long)e * NN * 128 + off;
        float2 v01 = __half22float2(*(const __half2*)p);
        float2 v23 = __half22float2(*(const __half2*)(p + 2));
        o0 += w * fmaxf(v01.x, 0.f);
        o1 += w * fmaxf(v01.y, 0.f);
        o2 += w * fmaxf(v23.x, 0.f);
        o3 += w * fmaxf(v23.y, 0.f);
    }
    o0 = o0 > 0.f ? o0 : __expf(o0) - 1.f;
    o1 = o1 > 0.f ? o1 : __expf(o1) - 1.f;
    o2 = o2 > 0.f ? o2 : __expf(o2) - 1.f;
    o3 = o3 > 0.f ? o3 : __expf(o3) - 1.f;
    __half* q = h1f + (long)t * NN * 128 + off;
    *(__half2*)q = __floats2half2_rn(o0, o1);
    *(__half2*)(q + 2) = __floats2half2_rn(o2, o3);
}

// ---------------- layer-2 attention dots (h2 in fp16; 1 head, 32 ch) --------------
__global__ __launch_bounds__(256)
void attn_dots2(const __half* __restrict__ h2h,
                const float* __restrict__ att_src,
                const float* __restrict__ att_dst,
                float* __restrict__ asrc, float* __restrict__ adst)
{
    int gid = blockIdx.x * 256 + threadIdx.x;
    int p = gid >> 5;
    int l = gid & 31;
    if (p >= 10 * NN) return;
    int e = p / NN, n = p - e * NN;
    int s = d_SRC[e], d = d_DST[e];
    float hs = __half2float(h2h[(long)(s * NN + n) * 32 + l]);
    float hd = __half2float(h2h[(long)(d * NN + n) * 32 + l]);
    float ps = hs * att_src[e * 32 + l];
    float pd = hd * att_dst[e * 32 + l];
#pragma unroll
    for (int off = 1; off < 32; off <<= 1) {
        ps += __shfl_xor(ps, off, 64);
        pd += __shfl_xor(pd, off, 64);
    }
    if (l == 0) { asrc[e * NN + n] = ps; adst[e * NN + n] = pd; }
}

// ---------------- layer-2 gather-aggregate: 32 lanes/node, 4 edge-slots ----------
__global__ __launch_bounds__(256)
void gather_agg2(const int* __restrict__ csr_off,
                 const unsigned short* __restrict__ csr_rows,
                 const __half* __restrict__ h2h,
                 const float* __restrict__ asrc, const float* __restrict__ adst,
                 __half* __restrict__ agg2h)
{
    int e = d_RORD[blockIdx.y];
    int node = blockIdx.x * 8 + (threadIdx.x >> 5);
    int lane = threadIdx.x & 31;
    if (node >= NN) return;
    const int* off = csr_off + e * (NN + 1);
    const unsigned short* rows = csr_rows + (long)e * NE;
    const __half* h2s = h2h + (long)d_SRC[e] * NN * 32;
    const float* as = asrc + e * NN;
    const int slot = lane >> 3;   // edge-slot (0..3)
    const int sub = lane & 7;     // channel group: channels 4*sub .. 4*sub+3
    float ad = adst[e * NN + node];
    int beg = off[node], end = off[node + 1];
    float den = (slot == 0) ? 1e-16f : 0.f;
    float a0 = 0.f, a1 = 0.f, a2 = 0.f, a3 = 0.f;

#define GA2_STEP(i)                                                              \
    {                                                                            \
        int e0 = (i) * 4 + slot;                                                 \
        float wi = __shfl(w, e0, 32);                                            \
        int ri = __shfl(r, e0, 32);                                              \
        h2x2 v = *(const h2x2*)(h2s + (long)ri * 32 + 4 * sub);                  \
        float2 f0 = __half22float2(v.a);                                         \
        float2 f1 = __half22float2(v.b);                                         \
        den += wi;                                                               \
        a0 += wi * f0.x; a1 += wi * f0.y; a2 += wi * f1.x; a3 += wi * f1.y;      \
    }

    for (int j0 = beg; j0 < end; j0 += 32) {
        int jj = j0 + lane;
        bool ok = jj < end;
        int r = (int)rows[ok ? jj : beg];
        float a = as[r] + ad;
        a = a > 0.f ? a : 0.2f * a;
        float w = ok ? __expf(a) : 0.f;
        int cnt = end - j0;
        if (cnt >= 32) {
            GA2_STEP(0) GA2_STEP(1) GA2_STEP(2) GA2_STEP(3)
            GA2_STEP(4) GA2_STEP(5) GA2_STEP(6) GA2_STEP(7)
        } else {
            int it = (cnt + 3) >> 2;
            for (int i = 0; i < it; ++i) GA2_STEP(i)
        }
    }
#undef GA2_STEP
#pragma unroll
    for (int m = 8; m < 32; m <<= 1) {
        a0 += __shfl_xor(a0, m, 32);
        a1 += __shfl_xor(a1, m, 32);
        a2 += __shfl_xor(a2, m, 32);
        a3 += __shfl_xor(a3, m, 32);
        den += __shfl_xor(den, m, 32);
    }
    if (slot == 0) {
        float inv = 1.0f / den;
        h2x2 o;
        o.a = __floats2half2_rn(a0 * inv, a1 * inv);
        o.b = __floats2half2_rn(a2 * inv, a3 * inv);
        *(h2x2*)(agg2h + ((long)e * NN + node) * 32 + 4 * sub) = o;
    }
}

// ---------------- semantic score + softmax over ALL types ----------------
__global__ void score_all_k(const float* __restrict__ colsum, const float* __restrict__ q,
                            float* __restrict__ sattn, int C)
{
    __shared__ float sc[10];
    int tid = threadIdx.x;
    if (tid < 10) {
        float s = 0.f;
        for (int c = 0; c < C; ++c) s += q[c] * colsum[tid * C + c];
        sc[tid] = s / (float)NN;
    }
    __syncthreads();
    if (tid < 4) {
        float mx = -1e30f;
        for (int m = 0; m < 10; ++m) if (d_DST[m] == tid) mx = fmaxf(mx, sc[m]);
        float ex[10];
        float sum = 0.f;
        for (int m = 0; m < 10; ++m) {
            ex[m] = 0.f;
            if (d_DST[m] == tid) { ex[m] = __expf(sc[m] - mx); sum += ex[m]; }
        }
        for (int m = 0; m < 10; ++m) if (d_DST[m] == tid) sattn[m] = ex[m] / sum;
    }
}

// ---------------- final: per-node channel softmax, fp16 agg in, fp32 out ----------
__global__ __launch_bounds__(256)
void final_softmax(const __half* __restrict__ agg, const float* __restrict__ sattn,
                   float* __restrict__ out)
{
    int gid = blockIdx.x * 256 + threadIdx.x;
    int c = gid & 31;
    int p = gid >> 5;
    if (p >= 4 * NN) return;
    int t = p / NN, n = p - t * NN;
    float f = 0.f;
    for (int m = 0; m < 10; ++m) {
        if (d_DST[m] != t) continue;
        f += sattn[m] * fmaxf(__half2float(agg[(long)(m * NN + n) * 32 + c]), 0.f);
    }
    float mx = f;
#pragma unroll
    for (int off = 1; off < 32; off <<= 1) mx = fmaxf(mx, __shfl_xor(mx, off, 64));
    float ex = __expf(f - mx);
    float sm = ex;
#pragma unroll
    for (int off = 1; off < 32; off <<= 1) sm += __shfl_xor(sm, off, 64);
    out[(long)(t * NN + n) * 32 + c] = ex / sm;
}

extern "C" void kernel_launch(void* const* d_in, const int* in_sizes, int n_in,
                              void* d_out, int out_size, void* d_ws, size_t ws_size,
                              hipStream_t stream) {
    const float* x[4] = {
        (const float*)d_in[0], (const float*)d_in[1],
        (const float*)d_in[2], (const float*)d_in[3]};
    const int* edges = (const int*)d_in[4];
    const float* W1    = (const float*)d_in[5];
    const float* b1    = (const float*)d_in[6];
    const float* att1s = (const float*)d_in[7];
    const float* att1d = (const float*)d_in[8];
    const float* k1W   = (const float*)d_in[9];
    const float* k1b   = (const float*)d_in[10];
    const float* q1    = (const float*)d_in[11];
    const float* W2    = (const float*)d_in[12];
    const float* b2    = (const float*)d_in[13];
    const float* att2s = (const float*)d_in[14];
    const float* att2d = (const float*)d_in[15];
    const float* k2W   = (const float*)d_in[16];
    const float* k2b   = (const float*)d_in[17];
    const float* q2    = (const float*)d_in[18];

    // ---- workspace layout (floats), peak ~170 MB ----
    float* W = (float*)d_ws;
    // region 0 [0, 15.36M floats):
    //   layer 1: h1h fp16 [4][NN][128]; after fusion: h1f overlays 0, h2h at 7.68M
    __half* h1h    = (__half*)W;
    __half* h1f    = (__half*)W;
    __half* h2h    = (__half*)(W + 7680000);
    // slots region [15.36M, 34.56M): slots16 fp16 [10][NN][128];
    //   CSR binned scratch overlays it before the gathers; agg2h overlays after fusion.
    __half* slots16 = (__half*)(W + 15360000);
    __half* agg2h  = (__half*)(W + 15360000);  // [10][NN][32] fp16 (slots16 dead)
    unsigned* binned = (unsigned*)(W + 15360000); // 10*59*12288 u32
    int*   binCur  = (int*)(W + 15360000 + 7249920);
    float* asrc1   = W + 34560000;           // 2.4M
    float* adst1   = W + 36960000;           // 2.4M (asrc2/adst2 overlay after layer 1)
    float* asrc2   = W + 36960000;           // 0.3M
    float* adst2   = W + 37260000;           // 0.3M
    float* colsum1 = W + 39360000;           // 1,280
    float* sattn1  = W + 39361280;           // 16
    float* colsum2 = W + 39361296;           // 320
    float* sattn2  = W + 39361616;           // 16
    int*   csr_off = (int*)(W + 39361640);   // 300,010 ints
    unsigned short* csr_row = (unsigned short*)(csr_off + 300016); // 4,000,000 u16

    // ---- CSR build (3 dispatches; bucket prefix folded into binB) ----
    init_k<<<7, 256, 0, stream>>>(binCur, colsum1);
    csr_binA<<<BPR * 10, 256, 0, stream>>>(edges, binCur, binned);
    csr_binB<<<NBUCK * 10, 256, 0, stream>>>(binCur, binned, csr_off, csr_row);

    // layer-1 projection: ONE dispatch for all 4 node types (BN=64, measured-best)
    proj1_k<<<dim3(235, 2, 4), 256, 0, stream>>>(
        x[0], x[1], x[2], x[3], W1, b1, h1h);

    attn_dots1<<<30000, 256, 0, stream>>>(h1h, att1s, att1d, asrc1, adst1);

    // ALL 10 relation gathers, ONE dispatch, XCD-pinned (1D grid = 8 x 9375)
    gather_agg1_all<<<75000, 256, 0, stream>>>(
        csr_off, csr_row, asrc1, adst1, h1h, slots16);

    // batched colsum over all 10 relations (fp16 A, BN=64, measured-best)
    mgemm_k<64><<<dim3(235, 2, 10), 256, 0, stream>>>(
        (const _Float16*)slots16, (long)NN * 128, k1W, 0, k1b, 0,
        colsum1, 128, NN, 128, 128, 1, 1);
    score_all_k<<<1, 64, 0, stream>>>(colsum1, q1, sattn1, 128);

    // batched fusion over 4 dst types -> h1f fp16
    fusion_all<<<dim3(3750, 4), 256, 0, stream>>>(slots16, sattn1, h1f);

    // layer-2 projection (batched z=4, fp16 A): h2h[t] = fp16( h1f[t] @ W2[t] + b2[t] )
    mgemm_k<32><<<dim3(235, 1, 4), 256, 0, stream>>>(
        (const _Float16*)h1f, (long)NN * 128, W2, 128L * 32, b2, 32,
        (float*)h2h, (long)NN * 16, NN, 128, 32, 0, 2);

    attn_dots2<<<37500, 256, 0, stream>>>(h2h, att2s, att2d, asrc2, adst2);
    gather_agg2<<<dim3(3750, 10), 256, 0, stream>>>(
        csr_off, csr_row, h2h, asrc2, adst2, agg2h);

    // batched colsum over all 10 relations (fp16 A)
    mgemm_k<32><<<dim3(235, 1, 10), 256, 0, stream>>>(
        (const _Float16*)agg2h, (long)NN * 32, k2W, 0, k2b, 0,
        colsum2, 32L, NN, 32, 32, 1, 1);
    score_all_k<<<1, 64, 0, stream>>>(colsum2, q2, sattn2, 32);
    final_softmax<<<15000, 256, 0, stream>>>(agg2h, sattn2, (float*)d_out);
}

// Round 15
// 705.747 us; speedup vs baseline: 1.0666x; 1.0074x over previous
//
#include <hip/hip_runtime.h>
#include <hip/hip_fp16.h>

#define NN 30000
#define NE 400000
#define NBUCK 59     // ceil(30000/512)
#define BPR 98       // blocks per relation in csr_binA: ceil(400000/4096)
#define EPB 4096     // edges per block in csr_binA
#define CAPREG 12288 // fixed slots per (rel,bucket) in binned scratch (mean 6827, sigma 82)
#define BCAP 12288   // LDS sort capacity in csr_binB

__constant__ int d_SRC[10] = {0,1,2,3,0,1,2,1,3,1};
__constant__ int d_DST[10] = {0,1,2,3,1,0,1,2,1,3};
// fusion tables: per dst type, relations ending there
__constant__ int d_FCNT[4] = {2,4,2,2};
__constant__ int d_FREL[4][4] = {{0,5,0,0},{1,4,6,8},{2,7,0,0},{3,9,0,0}};

// XCD-pinned schedule (both gathers): block g -> xcd = g%8 (HW round-robin),
// slot = g/8 in [0,9375). Each XCD serves at most 2 relations, so its L2 holds
// only 1-2 src slices. For gather2 the slices are 0.96MB -> fully L2-resident.
__constant__ int d_XRELA[8]  = {0,4,2,6,8,1,5,7};
__constant__ int d_XBASEA[8] = {0,1875,3750,5625,0,1875,3750,5625};
__constant__ int d_XCNTA[8]  = {7500,5625,3750,1875,7500,5625,3750,1875};
__constant__ int d_XRELB[8]  = {4,2,6,3,1,5,7,9};

typedef _Float16 f16x8 __attribute__((ext_vector_type(8)));
typedef float f32x4 __attribute__((ext_vector_type(4)));

struct __attribute__((aligned(8))) h2x2 { __half2 a, b; };

// ---------------- layer-1 projection: 4 node types, ONE dispatch (z selects x) ----
// BM=128, BK=32, BN=64 (measured-best shape); fp32 A -> fp16 staging; fp16 store.
__global__ __launch_bounds__(256)
void proj1_k(const float* __restrict__ A0, const float* __restrict__ A1,
             const float* __restrict__ A2, const float* __restrict__ A3,
             const float* __restrict__ B, const float* __restrict__ bias,
             __half* __restrict__ C)
{
    constexpr int BM = 128, BK = 32, MR = 2, NF = 4, LDK = BK + 8;
    constexpr int K = 256, N = 128, M = NN;
    const int z = blockIdx.z;
    const float* A = (z == 0) ? A0 : (z == 1) ? A1 : (z == 2) ? A2 : A3;
    const float* Bz = B + (long)z * K * N;
    const float* bz = bias + z * N;
    __half* Cz = C + (long)z * M * N;
    const int m0 = blockIdx.x * BM;
    const int n0 = blockIdx.y * 64;
    const int tid = threadIdx.x;
    const int wv = tid >> 6;
    const int l  = tid & 63;
    const int fm = l & 15;
    const int fg = l >> 4;

    __shared__ _Float16 As[BM][LDK];
    __shared__ _Float16 Bs[64][LDK];

    f32x4 acc[MR][NF];
#pragma unroll
    for (int mr = 0; mr < MR; ++mr)
#pragma unroll
        for (int f = 0; f < NF; ++f) acc[mr][f] = (f32x4){0.f, 0.f, 0.f, 0.f};

    const int arow = tid >> 1;
    const int akc  = (tid & 1) << 4;
    const int grow = m0 + arow;

    for (int k0 = 0; k0 < K; k0 += BK) {
        f16x8 ap0, ap1;
        if (grow < M) {
            const float* aq = A + (long)grow * K + k0 + akc;
            float4 u0 = *(const float4*)aq;
            float4 u1 = *(const float4*)(aq + 4);
            float4 u2 = *(const float4*)(aq + 8);
            float4 u3 = *(const float4*)(aq + 12);
            float v[16] = {u0.x,u0.y,u0.z,u0.w, u1.x,u1.y,u1.z,u1.w,
                           u2.x,u2.y,u2.z,u2.w, u3.x,u3.y,u3.z,u3.w};
#pragma unroll
            for (int j = 0; j < 8; ++j) { ap0[j] = (_Float16)v[j]; ap1[j] = (_Float16)v[j+8]; }
        } else {
#pragma unroll
            for (int j = 0; j < 8; ++j) { ap0[j] = (_Float16)0.f; ap1[j] = (_Float16)0.f; }
        }
        *(f16x8*)&As[arow][akc]     = ap0;
        *(f16x8*)&As[arow][akc + 8] = ap1;

        {
            const int bk = tid >> 4;
            const int bn = (tid & 15) << 2;
#pragma unroll
            for (int kk = 0; kk < 2; ++kk) {
                int kr = bk + kk * 16;
                float4 u = *(const float4*)(Bz + (long)(k0 + kr) * N + n0 + bn);
                Bs[bn + 0][kr] = (_Float16)u.x;
                Bs[bn + 1][kr] = (_Float16)u.y;
                Bs[bn + 2][kr] = (_Float16)u.z;
                Bs[bn + 3][kr] = (_Float16)u.w;
            }
        }
        __syncthreads();

        f16x8 a0 = *(const f16x8*)&As[wv * 32 + fm][fg * 8];
        f16x8 a1 = *(const f16x8*)&As[wv * 32 + 16 + fm][fg * 8];
#pragma unroll
        for (int f = 0; f < NF; ++f) {
            f16x8 b = *(const f16x8*)&Bs[f * 16 + fm][fg * 8];
            acc[0][f] = __builtin_amdgcn_mfma_f32_16x16x32_f16(a0, b, acc[0][f], 0, 0, 0);
            acc[1][f] = __builtin_amdgcn_mfma_f32_16x16x32_f16(a1, b, acc[1][f], 0, 0, 0);
        }
        __syncthreads();
    }

#pragma unroll
    for (int f = 0; f < NF; ++f) {
        float bzv = bz[n0 + f * 16 + fm];
#pragma unroll
        for (int mr = 0; mr < MR; ++mr)
#pragma unroll
            for (int i = 0; i < 4; ++i) {
                int gr = m0 + wv * 32 + mr * 16 + fg * 4 + i;
                if (gr < M) Cz[(long)gr * N + n0 + f * 16 + fm] = __float2half(acc[mr][f][i] + bzv);
            }
    }
}

// ---------------- MFMA GEMM (fp16 A): C[M,N] = act(A)[M,K] @ B[K,N] + bias ----
// BN in {64, 32}. epi=1: tanh + column-sum -> atomicAdd C[N]. epi=2: store fp16.
template<int BN>
__global__ __launch_bounds__(256)
void mgemm_k(const _Float16* __restrict__ Ah, long sA,
             const float* __restrict__ B, long sB,
             const float* __restrict__ bias, long sBias,
             float* __restrict__ C, long sC,
             int M, int K, int N, int relu_a, int epi)
{
    constexpr int BM = 128, BK = 32, MR = 2;
    constexpr int NF = BN / 16;
    constexpr int LDK = BK + 8;
    const int z = blockIdx.z;
    Ah += (long)z * sA;
    B += (long)z * sB;
    bias += (long)z * sBias;
    C += (long)z * sC;
    const int m0 = blockIdx.x * BM;
    const int n0 = blockIdx.y * BN;
    const int tid = threadIdx.x;
    const int wv = tid >> 6;
    const int l  = tid & 63;
    const int fm = l & 15;
    const int fg = l >> 4;

    __shared__ _Float16 As[BM][LDK];
    __shared__ _Float16 Bs[BN][LDK];
    __shared__ float red[4][BN];

    f32x4 acc[MR][NF];
#pragma unroll
    for (int mr = 0; mr < MR; ++mr)
#pragma unroll
        for (int f = 0; f < NF; ++f) acc[mr][f] = (f32x4){0.f, 0.f, 0.f, 0.f};

    const int arow = tid >> 1;
    const int akc  = (tid & 1) << 4;
    const int grow = m0 + arow;

    for (int k0 = 0; k0 < K; k0 += BK) {
        f16x8 ap0, ap1;
        if (grow < M) {
            const _Float16* aq = Ah + (long)grow * K + k0 + akc;
            ap0 = *(const f16x8*)aq;
            ap1 = *(const f16x8*)(aq + 8);
            if (relu_a) {
#pragma unroll
                for (int j = 0; j < 8; ++j) {
                    ap0[j] = ap0[j] > (_Float16)0.f ? ap0[j] : (_Float16)0.f;
                    ap1[j] = ap1[j] > (_Float16)0.f ? ap1[j] : (_Float16)0.f;
                }
            }
        } else {
#pragma unroll
            for (int j = 0; j < 8; ++j) { ap0[j] = (_Float16)0.f; ap1[j] = (_Float16)0.f; }
        }
        *(f16x8*)&As[arow][akc]     = ap0;
        *(f16x8*)&As[arow][akc + 8] = ap1;

        if constexpr (BN == 64) {
            const int bk = tid >> 4;
            const int bn = (tid & 15) << 2;
#pragma unroll
            for (int kk = 0; kk < 2; ++kk) {
                int kr = bk + kk * 16;
                float4 u = *(const float4*)(B + (long)(k0 + kr) * N + n0 + bn);
                Bs[bn + 0][kr] = (_Float16)u.x;
                Bs[bn + 1][kr] = (_Float16)u.y;
                Bs[bn + 2][kr] = (_Float16)u.z;
                Bs[bn + 3][kr] = (_Float16)u.w;
            }
        } else {                                 // BN == 32
            const int bk = tid >> 3;
            const int bn = (tid & 7) << 2;
            float4 u = *(const float4*)(B + (long)(k0 + bk) * N + n0 + bn);
            Bs[bn + 0][bk] = (_Float16)u.x;
            Bs[bn + 1][bk] = (_Float16)u.y;
            Bs[bn + 2][bk] = (_Float16)u.z;
            Bs[bn + 3][bk] = (_Float16)u.w;
        }
        __syncthreads();

        f16x8 a0 = *(const f16x8*)&As[wv * 32 + fm][fg * 8];
        f16x8 a1 = *(const f16x8*)&As[wv * 32 + 16 + fm][fg * 8];
#pragma unroll
        for (int f = 0; f < NF; ++f) {
            f16x8 b = *(const f16x8*)&Bs[f * 16 + fm][fg * 8];
            acc[0][f] = __builtin_amdgcn_mfma_f32_16x16x32_f16(a0, b, acc[0][f], 0, 0, 0);
            acc[1][f] = __builtin_amdgcn_mfma_f32_16x16x32_f16(a1, b, acc[1][f], 0, 0, 0);
        }
        __syncthreads();
    }

    if (epi == 2) {
        __half* Ch = (__half*)C;
#pragma unroll
        for (int f = 0; f < NF; ++f) {
            float bz = bias[n0 + f * 16 + fm];
#pragma unroll
            for (int mr = 0; mr < MR; ++mr)
#pragma unroll
                for (int i = 0; i < 4; ++i) {
                    int gr = m0 + wv * 32 + mr * 16 + fg * 4 + i;
                    if (gr < M) Ch[(long)gr * N + n0 + f * 16 + fm] = __float2half(acc[mr][f][i] + bz);
                }
        }
    } else {
#pragma unroll
        for (int f = 0; f < NF; ++f) {
            float bz = bias[n0 + f * 16 + fm];
            float s = 0.f;
#pragma unroll
            for (int mr = 0; mr < MR; ++mr)
#pragma unroll
                for (int i = 0; i < 4; ++i) {
                    int gr = m0 + wv * 32 + mr * 16 + fg * 4 + i;
                    if (gr < M) s += tanhf(acc[mr][f][i] + bz);
                }
            s += __shfl_xor(s, 16, 64);
            s += __shfl_xor(s, 32, 64);
            if (fg == 0) red[wv][f * 16 + fm] = s;
        }
        __syncthreads();
        if (tid < BN) {
            float s = red[0][tid] + red[1][tid] + red[2][tid] + red[3][tid];
            unsafeAtomicAdd(&C[n0 + tid], s);
        }
    }
}

// ---------------- init: bucket cursors + colsum zeroing ----------------
__global__ __launch_bounds__(256)
void init_k(int* __restrict__ binCur, float* __restrict__ colsum)
{
    int i = blockIdx.x * 256 + threadIdx.x;
    if (i < 10 * NBUCK) binCur[i] = (i % NBUCK) * CAPREG;
    if (i < 1632) colsum[i] = 0.f;
}

__global__ __launch_bounds__(256)
void csr_binA(const int* __restrict__ edges, int* __restrict__ binCur,
              unsigned* __restrict__ binned)
{
    __shared__ int lcnt[NBUCK];
    __shared__ int gbase[NBUCK];
    int rel = blockIdx.x / BPR;
    int blk = blockIdx.x - rel * BPR;
    int base = blk * EPB;
    int tid = threadIdx.x;
    for (int b = tid; b < NBUCK; b += 256) lcnt[b] = 0;
    __syncthreads();
    const int* er = edges + (long)rel * 2 * NE;
    const int* ec = er + NE;
    unsigned pk[16];
    unsigned mt[16];
#pragma unroll
    for (int k = 0; k < 16; ++k) {
        int i = base + k * 256 + tid;
        if (i < NE) {
            int r = er[i];
            int c = ec[i];
            int b = c >> 9;
            int lo = atomicAdd(&lcnt[b], 1);
            pk[k] = ((unsigned)c << 15) | (unsigned)r;
            mt[k] = ((unsigned)b << 16) | (unsigned)lo;
        } else {
            mt[k] = 0xFFFFFFFFu;
        }
    }
    __syncthreads();
    if (tid < NBUCK) gbase[tid] = atomicAdd(&binCur[rel * NBUCK + tid], lcnt[tid]);
    __syncthreads();
    unsigned* bn = binned + (long)rel * NBUCK * CAPREG;
#pragma unroll
    for (int k = 0; k < 16; ++k) {
        if (mt[k] != 0xFFFFFFFFu) {
            int b = mt[k] >> 16;
            int lo = mt[k] & 0xFFFF;
            bn[gbase[b] + lo] = pk[k];
        }
    }
}

// Pass B: per (rel,bucket) block: per-node histogram + scan -> csr_off segment;
// LDS sort; coalesced stream-out (u16 rows). Bucket CSR base computed inline.
__global__ __launch_bounds__(256)
void csr_binB(const int* __restrict__ binCur, const unsigned* __restrict__ binned,
              int* __restrict__ off_all, unsigned short* __restrict__ rows)
{
    __shared__ int cntS[512];
    __shared__ int lcur[512];
    __shared__ int part[256];
    __shared__ int buf[BCAP];
    int rel = blockIdx.x / NBUCK;
    int bkt = blockIdx.x - rel * NBUCK;
    const unsigned* bn = binned + ((long)rel * NBUCK + bkt) * CAPREG;
    int* off = off_all + rel * (NN + 1);
    unsigned short* rw = rows + (long)rel * NE;
    int cnt = binCur[rel * NBUCK + bkt] - bkt * CAPREG;
    int gbase = 0;
    for (int b = 0; b < bkt; ++b) gbase += binCur[rel * NBUCK + b] - b * CAPREG;
    int nb0 = bkt << 9;
    int nb1 = min(nb0 + 512, NN);
    int nloc = nb1 - nb0;
    int tid = threadIdx.x;
    if (bkt == 0 && tid == 0) off[NN] = NE;

    cntS[tid] = 0; cntS[tid + 256] = 0;
    __syncthreads();
    for (int j = tid; j < cnt; j += 256) {
        int c = (int)(bn[j] >> 15);
        atomicAdd(&cntS[c - nb0], 1);
    }
    __syncthreads();
    int c0 = cntS[2 * tid], c1 = cntS[2 * tid + 1];
    part[tid] = c0 + c1;
    __syncthreads();
    for (int d = 1; d < 256; d <<= 1) {
        int u = (tid >= d) ? part[tid - d] : 0;
        __syncthreads();
        part[tid] += u;
        __syncthreads();
    }
    int pre = (tid == 0) ? 0 : part[tid - 1];
    cntS[2 * tid] = pre;
    cntS[2 * tid + 1] = pre + c0;
    __syncthreads();
    for (int i = tid; i < nloc; i += 256) off[nb0 + i] = gbase + cntS[i];
    lcur[tid] = cntS[tid]; lcur[tid + 256] = cntS[tid + 256];
    __syncthreads();
    if (cnt <= BCAP) {
        for (int j = tid; j < cnt; j += 256) {
            unsigned p = bn[j];
            int r = (int)(p & 0x7FFF);
            int c = (int)(p >> 15);
            int pos = atomicAdd(&lcur[c - nb0], 1);
            buf[pos] = r;
        }
        __syncthreads();
        for (int i = tid; i < cnt; i += 256) rw[gbase + i] = (unsigned short)buf[i];
    } else {
        for (int j = tid; j < cnt; j += 256) {
            unsigned p = bn[j];
            int r = (int)(p & 0x7FFF);
            int c = (int)(p >> 15);
            int pos = atomicAdd(&lcur[c - nb0], 1);
            rw[gbase + pos] = (unsigned short)r;
        }
    }
}

// ---------------- layer-1 attention dots (h1 in fp16) ----------------
__global__ __launch_bounds__(256)
void attn_dots1(const __half* __restrict__ h1h,
                const float* __restrict__ att_src,
                const float* __restrict__ att_dst,
                float* __restrict__ asrc, float* __restrict__ adst)
{
    int gid = blockIdx.x * 256 + threadIdx.x;
    int wave = gid >> 6;
    int lane = gid & 63;
    if (wave >= 4 * NN) return;
    int t = wave / NN;
    int n = wave - t * NN;
    __half2 hh = *(const __half2*)&h1h[(long)(t * NN + n) * 128 + 2 * lane];
    float2 hv = __half22float2(hh);
    const int SRCc[10] = {0,1,2,3,0,1,2,1,3,1};
    const int DSTc[10] = {0,1,2,3,1,0,1,2,1,3};
#pragma unroll
    for (int e = 0; e < 10; ++e) {
        if (SRCc[e] == t) {
            float2 av = *(const float2*)&att_src[e * 128 + 2 * lane];
            float p = hv.x * av.x + hv.y * av.y;
#pragma unroll
            for (int off = 1; off < 8; off <<= 1) p += __shfl_xor(p, off, 64);
            if ((lane & 7) == 0) asrc[(long)(e * NN + n) * 8 + (lane >> 3)] = p;
        }
        if (DSTc[e] == t) {
            float2 bv = *(const float2*)&att_dst[e * 128 + 2 * lane];
            float p = hv.x * bv.x + hv.y * bv.y;
#pragma unroll
            for (int off = 1; off < 8; off <<= 1) p += __shfl_xor(p, off, 64);
            if ((lane & 7) == 0) adst[(long)(e * NN + n) * 8 + (lane >> 3)] = p;
        }
    }
}

// ---------------- layer-1 gather-aggregate: XCD-pinned, phase-A prefetch ----------
// Phase A: round of 8 edges, lane (eA,hA) computes one (edge,head) weight; next
// round's rows/asrc prefetched during FMA phase.
// Phase B: 4 edge-slots x 16 lanes x 8 channels (16B loads); shfl_xor(16,32).
__global__ __launch_bounds__(256)
void gather_agg1_all(const int* __restrict__ csr_off,
                     const unsigned short* __restrict__ csr_rows,
                     const float* __restrict__ asrc1, const float* __restrict__ adst1,
                     const __half* __restrict__ h1h, __half* __restrict__ slots16)
{
    int g = blockIdx.x;
    int xcd = g & 7;
    int slot = g >> 3;
    int e, i;
    if (slot < d_XCNTA[xcd]) { e = d_XRELA[xcd]; i = d_XBASEA[xcd] + slot; }
    else                     { e = d_XRELB[xcd]; i = slot - d_XCNTA[xcd]; }
    int node = i * 4 + (threadIdx.x >> 6);
    int lane = threadIdx.x & 63;
    if (node >= NN) return;
    const int* off = csr_off + e * (NN + 1);
    const unsigned short* rows = csr_rows + (long)e * NE;
    const float* asrc_e = asrc1 + (long)e * NN * 8;
    const float* adst_e = adst1 + (long)e * NN * 8;
    const _Float16* h1s = (const _Float16*)h1h + (long)d_SRC[e] * NN * 128;
    __half* out = slots16 + (long)e * NN * 128;

    const int g2  = lane >> 4;    // edge-slot (0..3)
    const int s16 = lane & 15;    // channel group: ch 8*s16 .. 8*s16+7
    const int hv  = s16 >> 1;     // head of those channels
    const int eA  = lane >> 3;    // phase-A edge
    const int hA  = lane & 7;     // phase-A head
    int beg = off[node], end = off[node + 1];
    float adA = adst_e[node * 8 + hA];
    float den = (g2 == 0) ? 1e-16f : 0.f;
    float a0 = 0.f, a1 = 0.f, a2 = 0.f, a3 = 0.f;
    float a4 = 0.f, a5 = 0.f, a6 = 0.f, a7 = 0.f;

#define GA1_STEP(i)                                                              \
    {                                                                            \
        int e0 = 4 * (i) + g2;                                                   \
        float wi = __shfl(w, e0 * 8 + hv, 64);                                   \
        int ri = __shfl(r, e0 * 8, 64);                                          \
        f16x8 v = *(const f16x8*)(h1s + (long)ri * 128 + 8 * s16);               \
        den += wi;                                                               \
        a0 += wi * (float)v[0]; a1 += wi * (float)v[1];                          \
        a2 += wi * (float)v[2]; a3 += wi * (float)v[3];                          \
        a4 += wi * (float)v[4]; a5 += wi * (float)v[5];                          \
        a6 += wi * (float)v[6]; a7 += wi * (float)v[7];                          \
    }

    if (beg < end) {
        int j0 = beg;
        int jj = j0 + eA;
        bool ok = jj < end;
        int r = (int)rows[ok ? jj : beg];
        float aw = asrc_e[r * 8 + hA] + adA;
        while (true) {
            float al = aw > 0.f ? aw : 0.2f * aw;
            float w = ok ? __expf(al) : 0.f;
            int j1 = j0 + 8;
            // prefetch next round's edge row + attention dot
            int rn = r; float awn = 0.f; bool okn = false;
            if (j1 < end) {
                int jn = j1 + eA;
                okn = jn < end;
                rn = (int)rows[okn ? jn : beg];
                awn = asrc_e[rn * 8 + hA] + adA;
            }
            int cnt = end - j0;
            GA1_STEP(0)
            if (cnt > 4) { GA1_STEP(1) }
            if (j1 >= end) break;
            j0 = j1; r = rn; aw = awn; ok = okn;
        }
    }
#undef GA1_STEP
#pragma unroll
    for (int m = 16; m < 64; m <<= 1) {
        a0 += __shfl_xor(a0, m, 64); a1 += __shfl_xor(a1, m, 64);
        a2 += __shfl_xor(a2, m, 64); a3 += __shfl_xor(a3, m, 64);
        a4 += __shfl_xor(a4, m, 64); a5 += __shfl_xor(a5, m, 64);
        a6 += __shfl_xor(a6, m, 64); a7 += __shfl_xor(a7, m, 64);
        den += __shfl_xor(den, m, 64);
    }
    if (g2 == 0) {
        float inv = 1.0f / den;
        f16x8 o;
        o[0] = (_Float16)(a0 * inv); o[1] = (_Float16)(a1 * inv);
        o[2] = (_Float16)(a2 * inv); o[3] = (_Float16)(a3 * inv);
        o[4] = (_Float16)(a4 * inv); o[5] = (_Float16)(a5 * inv);
        o[6] = (_Float16)(a6 * inv); o[7] = (_Float16)(a7 * inv);
        *(f16x8*)((_Float16*)out + (long)node * 128 + 8 * s16) = o;
    }
}

// ---------------- per-type fusion (batched): out = elu( sum sattn[e]*relu(slot_e) ) --
__global__ __launch_bounds__(256)
void fusion_all(const __half* __restrict__ slots16, const float* __restrict__ sattn,
                __half* __restrict__ h1f)
{
    int t = blockIdx.y;
    int idx = blockIdx.x * 256 + threadIdx.x;
    if (idx >= NN * 32) return;
    int c4 = idx & 31;
    int n = idx >> 5;
    long off = (long)n * 128 + c4 * 4;
    int cnt = d_FCNT[t];
    float o0 = 0.f, o1 = 0.f, o2 = 0.f, o3 = 0.f;
    for (int j = 0; j < cnt; ++j) {
        int e = d_FREL[t][j];
        float w = sattn[e];
        const __half* p = slots16 + (long)e * NN * 128 + off;
        float2 v01 = __half22float2(*(const __half2*)p);
        float2 v23 = __half22float2(*(const __half2*)(p + 2));
        o0 += w * fmaxf(v01.x, 0.f);
        o1 += w * fmaxf(v01.y, 0.f);
        o2 += w * fmaxf(v23.x, 0.f);
        o3 += w * fmaxf(v23.y, 0.f);
    }
    o0 = o0 > 0.f ? o0 : __expf(o0) - 1.f;
    o1 = o1 > 0.f ? o1 : __expf(o1) - 1.f;
    o2 = o2 > 0.f ? o2 : __expf(o2) - 1.f;
    o3 = o3 > 0.f ? o3 : __expf(o3) - 1.f;
    __half* q = h1f + (long)t * NN * 128 + off;
    *(__half2*)q = __floats2half2_rn(o0, o1);
    *(__half2*)(q + 2) = __floats2half2_rn(o2, o3);
}

// ---------------- layer-2 attention dots (h2 in fp16; 1 head, 32 ch) --------------
__global__ __launch_bounds__(256)
void attn_dots2(const __half* __restrict__ h2h,
                const float* __restrict__ att_src,
                const float* __restrict__ att_dst,
                float* __restrict__ asrc, float* __restrict__ adst)
{
    int gid = blockIdx.x * 256 + threadIdx.x;
    int p = gid >> 5;
    int l = gid & 31;
    if (p >= 10 * NN) return;
    int e = p / NN, n = p - e * NN;
    int s = d_SRC[e], d = d_DST[e];
    float hs = __half2float(h2h[(long)(s * NN + n) * 32 + l]);
    float hd = __half2float(h2h[(long)(d * NN + n) * 32 + l]);
    float ps = hs * att_src[e * 32 + l];
    float pd = hd * att_dst[e * 32 + l];
#pragma unroll
    for (int off = 1; off < 32; off <<= 1) {
        ps += __shfl_xor(ps, off, 64);
        pd += __shfl_xor(pd, off, 64);
    }
    if (l == 0) { asrc[e * NN + n] = ps; adst[e * NN + n] = pd; }
}

// ---------------- layer-2 gather-aggregate: XCD-pinned, 128-thread blocks --------
// Same pinned table as gather1 (4 nodes/block, 32 lanes/node). Each XCD's h2
// working set = 1-2 slices x 0.96MB -> fully L2-resident.
// Phase A: round of 32 edges, lane computes one weight. Phase B: 4 edge-slots x
// 8 lanes x 4 channels (8B loads). Combine via shfl_xor(8,16). fp16 output.
__global__ __launch_bounds__(128)
void gather_agg2(const int* __restrict__ csr_off,
                 const unsigned short* __restrict__ csr_rows,
                 const __half* __restrict__ h2h,
                 const float* __restrict__ asrc, const float* __restrict__ adst,
                 __half* __restrict__ agg2h)
{
    int g = blockIdx.x;
    int xcd = g & 7;
    int slot0 = g >> 3;
    int e, i;
    if (slot0 < d_XCNTA[xcd]) { e = d_XRELA[xcd]; i = d_XBASEA[xcd] + slot0; }
    else                      { e = d_XRELB[xcd]; i = slot0 - d_XCNTA[xcd]; }
    int node = i * 4 + (threadIdx.x >> 5);
    int lane = threadIdx.x & 31;
    if (node >= NN) return;
    const int* off = csr_off + e * (NN + 1);
    const unsigned short* rows = csr_rows + (long)e * NE;
    const __half* h2s = h2h + (long)d_SRC[e] * NN * 32;
    const float* as = asrc + e * NN;
    const int slot = lane >> 3;   // edge-slot (0..3)
    const int sub = lane & 7;     // channel group: channels 4*sub .. 4*sub+3
    float ad = adst[e * NN + node];
    int beg = off[node], end = off[node + 1];
    float den = (slot == 0) ? 1e-16f : 0.f;
    float a0 = 0.f, a1 = 0.f, a2 = 0.f, a3 = 0.f;

#define GA2_STEP(i)                                                              \
    {                                                                            \
        int e0 = (i) * 4 + slot;                                                 \
        float wi = __shfl(w, e0, 32);                                            \
        int ri = __shfl(r, e0, 32);                                              \
        h2x2 v = *(const h2x2*)(h2s + (long)ri * 32 + 4 * sub);                  \
        float2 f0 = __half22float2(v.a);                                         \
        float2 f1 = __half22float2(v.b);                                         \
        den += wi;                                                               \
        a0 += wi * f0.x; a1 += wi * f0.y; a2 += wi * f1.x; a3 += wi * f1.y;      \
    }

    for (int j0 = beg; j0 < end; j0 += 32) {
        int jj = j0 + lane;
        bool ok = jj < end;
        int r = (int)rows[ok ? jj : beg];
        float a = as[r] + ad;
        a = a > 0.f ? a : 0.2f * a;
        float w = ok ? __expf(a) : 0.f;
        int cnt = end - j0;
        if (cnt >= 32) {
            GA2_STEP(0) GA2_STEP(1) GA2_STEP(2) GA2_STEP(3)
            GA2_STEP(4) GA2_STEP(5) GA2_STEP(6) GA2_STEP(7)
        } else {
            int it = (cnt + 3) >> 2;
            for (int i = 0; i < it; ++i) GA2_STEP(i)
        }
    }
#undef GA2_STEP
#pragma unroll
    for (int m = 8; m < 32; m <<= 1) {
        a0 += __shfl_xor(a0, m, 32);
        a1 += __shfl_xor(a1, m, 32);
        a2 += __shfl_xor(a2, m, 32);
        a3 += __shfl_xor(a3, m, 32);
        den += __shfl_xor(den, m, 32);
    }
    if (slot == 0) {
        float inv = 1.0f / den;
        h2x2 o;
        o.a = __floats2half2_rn(a0 * inv, a1 * inv);
        o.b = __floats2half2_rn(a2 * inv, a3 * inv);
        *(h2x2*)(agg2h + ((long)e * NN + node) * 32 + 4 * sub) = o;
    }
}

// ---------------- semantic score + softmax over ALL types ----------------
__global__ void score_all_k(const float* __restrict__ colsum, const float* __restrict__ q,
                            float* __restrict__ sattn, int C)
{
    __shared__ float sc[10];
    int tid = threadIdx.x;
    if (tid < 10) {
        float s = 0.f;
        for (int c = 0; c < C; ++c) s += q[c] * colsum[tid * C + c];
        sc[tid] = s / (float)NN;
    }
    __syncthreads();
    if (tid < 4) {
        float mx = -1e30f;
        for (int m = 0; m < 10; ++m) if (d_DST[m] == tid) mx = fmaxf(mx, sc[m]);
        float ex[10];
        float sum = 0.f;
        for (int m = 0; m < 10; ++m) {
            ex[m] = 0.f;
            if (d_DST[m] == tid) { ex[m] = __expf(sc[m] - mx); sum += ex[m]; }
        }
        for (int m = 0; m < 10; ++m) if (d_DST[m] == tid) sattn[m] = ex[m] / sum;
    }
}

// ---------------- final: per-node channel softmax, fp16 agg in, fp32 out ----------
__global__ __launch_bounds__(256)
void final_softmax(const __half* __restrict__ agg, const float* __restrict__ sattn,
                   float* __restrict__ out)
{
    int gid = blockIdx.x * 256 + threadIdx.x;
    int c = gid & 31;
    int p = gid >> 5;
    if (p >= 4 * NN) return;
    int t = p / NN, n = p - t * NN;
    float f = 0.f;
    for (int m = 0; m < 10; ++m) {
        if (d_DST[m] != t) continue;
        f += sattn[m] * fmaxf(__half2float(agg[(long)(m * NN + n) * 32 + c]), 0.f);
    }
    float mx = f;
#pragma unroll
    for (int off = 1; off < 32; off <<= 1) mx = fmaxf(mx, __shfl_xor(mx, off, 64));
    float ex = __expf(f - mx);
    float sm = ex;
#pragma unroll
    for (int off = 1; off < 32; off <<= 1) sm += __shfl_xor(sm, off, 64);
    out[(long)(t * NN + n) * 32 + c] = ex / sm;
}

extern "C" void kernel_launch(void* const* d_in, const int* in_sizes, int n_in,
                              void* d_out, int out_size, void* d_ws, size_t ws_size,
                              hipStream_t stream) {
    const float* x[4] = {
        (const float*)d_in[0], (const float*)d_in[1],
        (const float*)d_in[2], (const float*)d_in[3]};
    const int* edges = (const int*)d_in[4];
    const float* W1    = (const float*)d_in[5];
    const float* b1    = (const float*)d_in[6];
    const float* att1s = (const float*)d_in[7];
    const float* att1d = (const float*)d_in[8];
    const float* k1W   = (const float*)d_in[9];
    const float* k1b   = (const float*)d_in[10];
    const float* q1    = (const float*)d_in[11];
    const float* W2    = (const float*)d_in[12];
    const float* b2    = (const float*)d_in[13];
    const float* att2s = (const float*)d_in[14];
    const float* att2d = (const float*)d_in[15];
    const float* k2W   = (const float*)d_in[16];
    const float* k2b   = (const float*)d_in[17];
    const float* q2    = (const float*)d_in[18];

    // ---- workspace layout (floats), peak ~170 MB ----
    float* W = (float*)d_ws;
    // region 0 [0, 15.36M floats):
    //   layer 1: h1h fp16 [4][NN][128]; after fusion: h1f overlays 0, h2h at 7.68M
    __half* h1h    = (__half*)W;
    __half* h1f    = (__half*)W;
    __half* h2h    = (__half*)(W + 7680000);
    // slots region [15.36M, 34.56M): slots16 fp16 [10][NN][128];
    //   CSR binned scratch overlays it before the gathers; agg2h overlays after fusion.
    __half* slots16 = (__half*)(W + 15360000);
    __half* agg2h  = (__half*)(W + 15360000);  // [10][NN][32] fp16 (slots16 dead)
    unsigned* binned = (unsigned*)(W + 15360000); // 10*59*12288 u32
    int*   binCur  = (int*)(W + 15360000 + 7249920);
    float* asrc1   = W + 34560000;           // 2.4M
    float* adst1   = W + 36960000;           // 2.4M (asrc2/adst2 overlay after layer 1)
    float* asrc2   = W + 36960000;           // 0.3M
    float* adst2   = W + 37260000;           // 0.3M
    float* colsum1 = W + 39360000;           // 1,280
    float* sattn1  = W + 39361280;           // 16
    float* colsum2 = W + 39361296;           // 320
    float* sattn2  = W + 39361616;           // 16
    int*   csr_off = (int*)(W + 39361640);   // 300,010 ints
    unsigned short* csr_row = (unsigned short*)(csr_off + 300016); // 4,000,000 u16

    // ---- CSR build (3 dispatches; bucket prefix folded into binB) ----
    init_k<<<7, 256, 0, stream>>>(binCur, colsum1);
    csr_binA<<<BPR * 10, 256, 0, stream>>>(edges, binCur, binned);
    csr_binB<<<NBUCK * 10, 256, 0, stream>>>(binCur, binned, csr_off, csr_row);

    // layer-1 projection: ONE dispatch for all 4 node types (BN=64, measured-best)
    proj1_k<<<dim3(235, 2, 4), 256, 0, stream>>>(
        x[0], x[1], x[2], x[3], W1, b1, h1h);

    attn_dots1<<<30000, 256, 0, stream>>>(h1h, att1s, att1d, asrc1, adst1);

    // ALL 10 relation gathers, ONE dispatch, XCD-pinned (1D grid = 8 x 9375)
    gather_agg1_all<<<75000, 256, 0, stream>>>(
        csr_off, csr_row, asrc1, adst1, h1h, slots16);

    // batched colsum over all 10 relations (fp16 A, BN=64, measured-best)
    mgemm_k<64><<<dim3(235, 2, 10), 256, 0, stream>>>(
        (const _Float16*)slots16, (long)NN * 128, k1W, 0, k1b, 0,
        colsum1, 128, NN, 128, 128, 1, 1);
    score_all_k<<<1, 64, 0, stream>>>(colsum1, q1, sattn1, 128);

    // batched fusion over 4 dst types -> h1f fp16
    fusion_all<<<dim3(3750, 4), 256, 0, stream>>>(slots16, sattn1, h1f);

    // layer-2 projection (batched z=4, fp16 A): h2h[t] = fp16( h1f[t] @ W2[t] + b2[t] )
    mgemm_k<32><<<dim3(235, 1, 4), 256, 0, stream>>>(
        (const _Float16*)h1f, (long)NN * 128, W2, 128L * 32, b2, 32,
        (float*)h2h, (long)NN * 16, NN, 128, 32, 0, 2);

    attn_dots2<<<37500, 256, 0, stream>>>(h2h, att2s, att2d, asrc2, adst2);

    // ALL 10 relation gathers, ONE dispatch, XCD-pinned (128-thread blocks)
    gather_agg2<<<75000, 128, 0, stream>>>(
        csr_off, csr_row, h2h, asrc2, adst2, agg2h);

    // batched colsum over all 10 relations (fp16 A)
    mgemm_k<32><<<dim3(235, 1, 10), 256, 0, stream>>>(
        (const _Float16*)agg2h, (long)NN * 32, k2W, 0, k2b, 0,
        colsum2, 32L, NN, 32, 32, 1, 1);
    score_all_k<<<1, 64, 0, stream>>>(colsum2, q2, sattn2, 32);
    final_softmax<<<15000, 256, 0, stream>>>(agg2h, sattn2, (float*)d_out);
}